// Round 1
// 536.693 us; speedup vs baseline: 1.3588x; 1.3588x over previous
//
#include <hip/hip_runtime.h>

typedef unsigned short u16;
typedef unsigned int u32;
typedef __bf16 bf16x8 __attribute__((ext_vector_type(8)));
typedef float f32x4 __attribute__((ext_vector_type(4)));

#define HP 258
// weight-table element offsets within ws (u16 units)
#define E_WT0 0
#define E_WT1 37120
#define E_WT2 46592
#define E_WTF 56064
// per-batch tensor byte offsets within ws (total footprint 29,951,744 B; ws >= 55.3 MB verified R6/R8)
#define OFF_INPT 131072ull
#define OFF_HT   17171456ull   // OFF_INPT + 258*258*128*2
#define OFF_T1   21431552ull   // OFF_HT + 258*258*32*2
#define OFF_FEA  25691648ull   // OFF_T1 + 258*258*32*2
#define WS_NEED  29951744ull

__device__ __forceinline__ float bf2f(u16 u){ u32 x = ((u32)u) << 16; return __builtin_bit_cast(float, x); }
__device__ __forceinline__ u16 f2bf(float f){
  u32 x = __builtin_bit_cast(u32, f);
  return (u16)((x + 0x7fffu + ((x >> 16) & 1u)) >> 16);   // RNE
}
__device__ __forceinline__ u32 pack2(float a, float b){ return (u32)f2bf(a) | ((u32)f2bf(b) << 16); }
__device__ __forceinline__ float lrelu(float x){ return x >= 0.f ? x : 0.1f * x; }

__global__ void k_sent(float* __restrict__ out, float val){
  if (threadIdx.x == 0 && blockIdx.x == 0) out[0] = val;
}

// ---------------- halo-ring zeroing for all four per-batch buffers (once per launch) ----------
__global__ __launch_bounds__(256) void k_halo(char* __restrict__ ws){
  int idx = blockIdx.x * 256 + threadIdx.x;
  if (idx >= 258 * 258) return;
  int y = idx / 258;
  int x = idx - y * 258;
  if (y != 0 && y != 257 && x != 0 && x != 257) return;
  uint4 z = make_uint4(0u, 0u, 0u, 0u);
  size_t pix = (size_t)idx;
  uint4* p0 = (uint4*)(ws + OFF_INPT + pix * 256);
  #pragma unroll
  for (int k = 0; k < 16; k++) p0[k] = z;
  uint4* p1 = (uint4*)(ws + OFF_HT + pix * 64);
  uint4* p2 = (uint4*)(ws + OFF_T1 + pix * 64);
  uint4* p3 = (uint4*)(ws + OFF_FEA + pix * 64);
  #pragma unroll
  for (int k = 0; k < 4; k++){ p1[k] = z; p2[k] = z; p3[k] = z; }
}

// ---------------- weight re-layout: Wt[co][tap*Cpad + c], tap-major K, channel-permuted -------
// inpT channel order: 0..31 up-feat, 32..33 flow, 34..114 corr(dy*9+dx), 115..127 zero.
// Original (R8-verified) w0 input-channel order: 0..80 corr, 81..112 feat, 113..114 flow.
__global__ __launch_bounds__(256) void k_wprep(const float* __restrict__ w0, const float* __restrict__ w1,
    const float* __restrict__ w2, const float* __restrict__ wf, u16* __restrict__ wse){
  for (int idx = blockIdx.x * 256 + threadIdx.x; idx < 60800; idx += 64 * 256){
    float v = 0.f;
    if (idx < 37120){                       // Wt0: 32 rows x 1160 (K=9*128=1152 used)
      int co = idx / 1160, kk = idx % 1160;
      if (kk < 1152){
        int tap = kk >> 7, c = kk & 127;
        if (c < 115){
          int oc = (c < 34) ? (81 + c) : (c - 34);
          v = w0[(co * 115 + oc) * 9 + tap];
        }
      }
    } else if (idx < 46592){                // Wt1: 32 x 296 (K=9*32=288)
      int r = idx - 37120; int co = r / 296, kk = r % 296;
      if (kk < 288){ int tap = kk >> 5, c = kk & 31; v = w1[(co * 32 + c) * 9 + tap]; }
    } else if (idx < 56064){                // Wt2
      int r = idx - 46592; int co = r / 296, kk = r % 296;
      if (kk < 288){ int tap = kk >> 5, c = kk & 31; v = w2[(co * 32 + c) * 9 + tap]; }
    } else {                                // Wtf: 16 x 296, rows 3..15 zero
      int r = idx - 56064; int co = r / 296, kk = r % 296;
      if (kk < 288 && co < 3){ int tap = kk >> 5, c = kk & 31; v = wf[(co * 32 + c) * 9 + tap]; }
    }
    wse[idx] = f2bf(v);
  }
}

// ---------------- fused correlation + 2x bilinear upsample -> inpT [258][258][128] bf16 -------
// R9 restructure for occupancy: grid = 6 P-groups x 2 half-rows x 256 rows = 3072 blocks.
// P 0..3: corr dy {2P, 2P+1}; P=4: corr dy 8; P=5: 34-channel bilinear upsample.
// ref held in registers (no refL LDS); nbL is the only LDS (9.2 KB) -> ~12 resident waves/CU.
// bx % 8 == row-band keeps all blocks of a row on one XCD (write-sector + L2 locality).

// one dy slice: stage nb row into nbL (bf16), then 32-ch x 9-dx x 2-px FMA into ACC.
#define CORR_DY(DYH, ACC) { \
    const int ih = h + (2 * P + (DYH)) - 4; \
    if (DYH) __syncthreads();              /* previous-slice readers done */ \
    const bool oob = (ih < 0) || (ih > 255); \
    _Pragma("unroll") \
    for (int k = 0; k < 18; k++){ \
      int id = t + 64 * k;                 /* 0..1151 = 32 ch x 36 float4 */ \
      int c = id / 36, q = id - c * 36; \
      int icol = p0 - 8 + q * 4; \
      ushort4 s = make_ushort4(0, 0, 0, 0); \
      if (!oob && icol >= 0 && icol <= 252){ \
        float4 v = *(const float4*)(xnb + ((size_t)(bio * 32 + c)) * 65536 + (size_t)ih * 256 + icol); \
        s = make_ushort4(f2bf(v.x), f2bf(v.y), f2bf(v.z), f2bf(v.w)); \
      } \
      *((ushort4*)&nbL[c][q * 4]) = s; \
    } \
    __syncthreads(); \
    _Pragma("unroll") \
    for (int c = 0; c < 32; c++){ \
      u32 wd[5]; \
      _Pragma("unroll") \
      for (int j = 0; j < 5; j++) wd[j] = *(const u32*)&nbL[c][2 * t + 4 + 2 * j]; \
      float win[10]; \
      _Pragma("unroll") \
      for (int k2 = 0; k2 < 10; k2++) win[k2] = bf2f((u16)(wd[k2 >> 1] >> (16 * (k2 & 1)))); \
      _Pragma("unroll") \
      for (int dx = 0; dx < 9; dx++){ \
        ACC[dx][0] = fmaf(rv0[c], win[dx],     ACC[dx][0]); \
        ACC[dx][1] = fmaf(rv1[c], win[dx + 1], ACC[dx][1]); \
      } \
    } \
  }

__global__ __launch_bounds__(64) void k_corr_up(
    const float* __restrict__ xref, const float* __restrict__ xnb,
    const float* __restrict__ bflow, const float* __restrict__ bfeat,
    char* __restrict__ ws, int bio){
  __shared__ __align__(16) u16 nbL[32][144];   // cols [p0-8, p0+136), stride 288 B
  const int t = threadIdx.x;
  const int bx = blockIdx.x;
  const int P  = bx >> 9;                      // 0..5
  const int hf = (bx >> 8) & 1;                // half-row
  const int r  = bx & 255;
  const int h  = (r & 7) * 32 + (r >> 3);      // XCD swizzle: 32-row bands per XCD
  const int p0 = hf * 128;

  size_t pxb[2];
  #pragma unroll
  for (int p = 0; p < 2; p++)
    pxb[p] = OFF_INPT + ((size_t)(h + 1) * 258 + (p0 + 2 * t + p + 1)) * 256;

  // ---- P=5: channels 0..33, bilinear 2x upsample (half-pixel, edge clamp), flow *2 ----
  if (P == 5){
    int y0 = (h >> 1) - 1 + (h & 1);
    float fyv = (h & 1) ? 0.25f : 0.75f;
    int y0c = y0 < 0 ? 0 : y0;
    int y1c = (y0 + 1) > 127 ? 127 : (y0 + 1);
    int y0o = y0c * 128, y1o = y1c * 128;
    int x0c[2], x1c[2]; float fxv[2];
    #pragma unroll
    for (int p = 0; p < 2; p++){
      int w = p0 + 2 * t + p; int x0 = (w >> 1) - 1 + (w & 1);
      fxv[p] = (w & 1) ? 0.25f : 0.75f;
      x0c[p] = x0 < 0 ? 0 : x0;
      x1c[p] = (x0 + 1) > 127 ? 127 : (x0 + 1);
    }
    for (int d = 0; d < 17; d++){
      #pragma unroll
      for (int p = 0; p < 2; p++){
        float vv[2];
        #pragma unroll
        for (int e = 0; e < 2; e++){
          int c = 2 * d + e;
          const float* pl = (c < 32) ? (bfeat + ((size_t)(bio * 32 + c)) * 16384)
                                     : (bflow + ((size_t)(bio * 2 + (c - 32))) * 16384);
          float v00 = pl[y0o + x0c[p]], v01 = pl[y0o + x1c[p]];
          float v10 = pl[y1o + x0c[p]], v11 = pl[y1o + x1c[p]];
          float r0 = v00 + fxv[p] * (v01 - v00);
          float r1 = v10 + fxv[p] * (v11 - v10);
          float v = r0 + fyv * (r1 - r0);
          vv[e] = (c >= 32) ? v * 2.f : v;
        }
        *(u32*)(ws + pxb[p] + 4 * d) = pack2(vv[0], vv[1]);
      }
    }
    return;
  }

  // ---- corr P-groups: ref pixels live in registers (f32), statically indexed ----
  float rv0[32], rv1[32];
  #pragma unroll
  for (int c = 0; c < 32; c++){
    float2 v = *(const float2*)(xref + ((size_t)(bio * 32 + c)) * 65536 + (size_t)h * 256 + p0 + 2 * t);
    rv0[c] = v.x; rv1[c] = v.y;
  }

  float acc0[9][2] = {};
  float acc1[9][2] = {};
  CORR_DY(0, acc0)
  if (P < 4){
    CORR_DY(1, acc1)
  }

  // store: corr value = lrelu(acc/32); inpT channel 34 + dy*9 + dx
  if (P < 4){
    #pragma unroll
    for (int p = 0; p < 2; p++)
      #pragma unroll
      for (int d = 0; d < 9; d++){
        float lo = lrelu(((2 * d < 9)     ? acc0[2 * d][p]     : acc1[2 * d - 9][p])     * 0.03125f);
        float hi = lrelu(((2 * d + 1 < 9) ? acc0[2 * d + 1][p] : acc1[2 * d + 1 - 9][p]) * 0.03125f);
        *(u32*)(ws + pxb[p] + 68 + 36 * P + 4 * d) = pack2(lo, hi);
      }
  } else {
    #pragma unroll
    for (int p = 0; p < 2; p++)
      #pragma unroll
      for (int d = 0; d < 11; d++){
        float lo = (2 * d < 9)     ? lrelu(acc0[2 * d][p] * 0.03125f)     : 0.f;
        float hi = (2 * d + 1 < 9) ? lrelu(acc0[2 * d + 1][p] * 0.03125f) : 0.f;
        *(u32*)(ws + pxb[p] + 212 + 4 * d) = pack2(lo, hi);   // ch 106..114 + zero pad to 127
      }
  }
}

// ---------------- conv0: 128->32, MFMA implicit GEMM, weights LDS-chunked ---------------------
__global__ __launch_bounds__(256) void k_conv0(const u16* __restrict__ inT, const u16* __restrict__ wt,
    const float* __restrict__ bias, u16* __restrict__ outA){
  __shared__ __align__(16) u16 wl[32 * 648];
  const int tid = threadIdx.x;
  const int bx = blockIdx.x;
  const int row = (bx & 7) * 32 + (bx >> 3);
  const int wv = tid >> 6, ln = tid & 63, l15 = ln & 15, l4 = ln >> 4;
  f32x4 acc[4][2] = {};
  const u16* aB[4];
  #pragma unroll
  for (int i = 0; i < 4; i++)
    aB[i] = inT + (size_t)(row * HP + (wv * 64 + i * 16 + l15)) * 128 + l4 * 8;

  // chunk 0: taps 0..3 (512 k-elems/row)
  for (int i = tid; i < 2048; i += 256){
    int co = i >> 6, q = i & 63;
    ((uint4*)&wl[co * 648])[q] = *(const uint4*)&wt[co * 1160 + q * 8];
  }
  __syncthreads();
  #pragma unroll
  for (int tap = 0; tap < 4; tap++){
    const int ky = tap / 3, kx = tap % 3;
    #pragma unroll
    for (int s = 0; s < 4; s++){
      bf16x8 bv[2];
      #pragma unroll
      for (int j = 0; j < 2; j++){
        uint4 u = *(const uint4*)&wl[(j * 16 + l15) * 648 + tap * 128 + s * 32 + l4 * 8];
        bv[j] = __builtin_bit_cast(bf16x8, u);
      }
      #pragma unroll
      for (int i = 0; i < 4; i++){
        uint4 ua = *(const uint4*)(aB[i] + (ky * HP + kx) * 128 + s * 32);
        bf16x8 av = __builtin_bit_cast(bf16x8, ua);
        #pragma unroll
        for (int j = 0; j < 2; j++)
          acc[i][j] = __builtin_amdgcn_mfma_f32_16x16x32_bf16(av, bv[j], acc[i][j], 0, 0, 0);
      }
    }
  }
  __syncthreads();
  // chunk 1: taps 4..8 (640 k-elems/row)
  for (int i = tid; i < 2560; i += 256){
    int co = i / 80, q = i % 80;
    ((uint4*)&wl[co * 648])[q] = *(const uint4*)&wt[co * 1160 + 512 + q * 8];
  }
  __syncthreads();
  #pragma unroll
  for (int tap = 4; tap < 9; tap++){
    const int ky = tap / 3, kx = tap % 3;
    #pragma unroll
    for (int s = 0; s < 4; s++){
      bf16x8 bv[2];
      #pragma unroll
      for (int j = 0; j < 2; j++){
        uint4 u = *(const uint4*)&wl[(j * 16 + l15) * 648 + (tap - 4) * 128 + s * 32 + l4 * 8];
        bv[j] = __builtin_bit_cast(bf16x8, u);
      }
      #pragma unroll
      for (int i = 0; i < 4; i++){
        uint4 ua = *(const uint4*)(aB[i] + (ky * HP + kx) * 128 + s * 32);
        bf16x8 av = __builtin_bit_cast(bf16x8, ua);
        #pragma unroll
        for (int j = 0; j < 2; j++)
          acc[i][j] = __builtin_amdgcn_mfma_f32_16x16x32_bf16(av, bv[j], acc[i][j], 0, 0, 0);
      }
    }
  }
  // epilogue: bias + lrelu -> hT halo layout (bf16)
  #pragma unroll
  for (int i = 0; i < 4; i++){
    const int pxb = wv * 64 + i * 16 + l4 * 4;
    #pragma unroll
    for (int j = 0; j < 2; j++){
      const int co = j * 16 + l15;
      const float bs = bias[co];
      #pragma unroll
      for (int r = 0; r < 4; r++){
        const int px = pxb + r;
        float v = lrelu(acc[i][j][r] + bs);
        outA[(size_t)((row + 1) * HP + px + 1) * 32 + co] = f2bf(v);
      }
    }
  }
}

// ---------------- 32-cin convs (conv1/conv2/convf), MFMA -------------------------------------
// MODE 0: bias+lrelu -> halo outH (t1). MODE 1: +resid, lrelu -> halo outH (fea) AND fp32 out feats.
// MODE 2: flows (co 0,1) + sigmoid mask (co 2) -> fp32 out.
template<int NT, int MODE>
__global__ __launch_bounds__(256) void k_conv32(const u16* __restrict__ inT, const u16* __restrict__ wt,
    const float* __restrict__ bias, u16* __restrict__ outH, float* __restrict__ outF,
    const u16* __restrict__ resid, int bio){
  constexpr int NR = (NT == 2) ? 32 : 16;
  __shared__ __align__(16) u16 wl[NR * 296];
  const int tid = threadIdx.x;
  for (int i = tid; i < NR * 296 / 8; i += 256)
    ((uint4*)wl)[i] = ((const uint4*)wt)[i];
  __syncthreads();
  const int bx = blockIdx.x;
  const int row = (bx & 7) * 32 + (bx >> 3);
  const int wv = tid >> 6, ln = tid & 63, l15 = ln & 15, l4 = ln >> 4;
  f32x4 acc[4][NT] = {};
  const u16* aB[4];
  #pragma unroll
  for (int i = 0; i < 4; i++)
    aB[i] = inT + (size_t)(row * HP + (wv * 64 + i * 16 + l15)) * 32 + l4 * 8;
  #pragma unroll
  for (int ky = 0; ky < 3; ky++){
    #pragma unroll
    for (int kx = 0; kx < 3; kx++){
      const int tap = ky * 3 + kx;
      bf16x8 bv[NT];
      #pragma unroll
      for (int j = 0; j < NT; j++){
        uint4 u = *(const uint4*)&wl[(j * 16 + l15) * 296 + tap * 32 + l4 * 8];
        bv[j] = __builtin_bit_cast(bf16x8, u);
      }
      #pragma unroll
      for (int i = 0; i < 4; i++){
        uint4 ua = *(const uint4*)(aB[i] + (ky * HP + kx) * 32);
        bf16x8 av = __builtin_bit_cast(bf16x8, ua);
        #pragma unroll
        for (int j = 0; j < NT; j++)
          acc[i][j] = __builtin_amdgcn_mfma_f32_16x16x32_bf16(av, bv[j], acc[i][j], 0, 0, 0);
      }
    }
  }
  #pragma unroll
  for (int i = 0; i < 4; i++){
    const int pxb = wv * 64 + i * 16 + l4 * 4;
    #pragma unroll
    for (int j = 0; j < NT; j++){
      const int co = j * 16 + l15;
      float bs;
      if constexpr (MODE == 2) bs = (co < 3) ? bias[co] : 0.f;
      else bs = bias[co];
      #pragma unroll
      for (int r = 0; r < 4; r++){
        const int px = pxb + r;
        float v = acc[i][j][r] + bs;
        if constexpr (MODE == 0){
          v = lrelu(v);
          outH[(size_t)((row + 1) * HP + px + 1) * 32 + co] = f2bf(v);
        } else if constexpr (MODE == 1){
          float hres = bf2f(resid[(size_t)((row + 1) * HP + px + 1) * 32 + co]);
          v = lrelu(v + hres);
          outH[(size_t)((row + 1) * HP + px + 1) * 32 + co] = f2bf(v);                  // feaT
          outF[786432 + ((size_t)(bio * 32 + co)) * 65536 + (size_t)row * 256 + px] = v; // feats
        } else {
          if (co < 2)
            outF[((size_t)(bio * 2 + co)) * 65536 + (size_t)row * 256 + px] = v;        // flows
          else if (co == 2){
            float s = 1.f / (1.f + __expf(-v));
            outF[524288 + (size_t)bio * 65536 + (size_t)row * 256 + px] = s;            // mask
          }
        }
      }
    }
  }
}

extern "C" void kernel_launch(void* const* d_in, const int* in_sizes, int n_in,
                              void* d_out, int out_size, void* d_ws, size_t ws_size,
                              hipStream_t stream){
  float* out = (float*)d_out;

  // ---- runtime interface verification (kept from R6; encodes any mismatch into out[0]) ----
  static const int exp_sizes[12] = {8388608, 8388608, 131072, 2097152,
                                    33120, 32, 9216, 32, 9216, 32, 864, 3};
  float sent = 0.f;
  if (n_in != 12) sent = 1.0e6f;
  else if (out_size != 9175040) sent = 2.0e6f;
  else {
    for (int i = 0; i < 12; i++)
      if (in_sizes[i] != exp_sizes[i]){ sent = 3.0e6f * (1.0f + 0.01f * i); break; }
    if (sent == 0.f && ws_size < WS_NEED)
      sent = 16.0f * (float)(ws_size >> 20);
  }
  if (sent != 0.f){
    hipLaunchKernelGGL(k_sent, dim3(1), dim3(64), 0, stream, out, sent);
    return;
  }

  const float* xref  = (const float*)d_in[0];
  const float* xnb   = (const float*)d_in[1];
  const float* bflow = (const float*)d_in[2];
  const float* bfeat = (const float*)d_in[3];
  const float* w0 = (const float*)d_in[4];
  const float* b0 = (const float*)d_in[5];
  const float* w1 = (const float*)d_in[6];
  const float* b1 = (const float*)d_in[7];
  const float* w2 = (const float*)d_in[8];
  const float* b2 = (const float*)d_in[9];
  const float* wf = (const float*)d_in[10];
  const float* bf = (const float*)d_in[11];
  char* ws = (char*)d_ws;
  u16* wse  = (u16*)d_ws;
  u16* inpT = (u16*)(ws + OFF_INPT);
  u16* hT   = (u16*)(ws + OFF_HT);
  u16* t1T  = (u16*)(ws + OFF_T1);
  u16* feaT = (u16*)(ws + OFF_FEA);

  hipLaunchKernelGGL(k_halo, dim3(261), dim3(256), 0, stream, ws);
  hipLaunchKernelGGL(k_wprep, dim3(64), dim3(256), 0, stream, w0, w1, w2, wf, wse);
  for (int bio = 0; bio < 4; bio++){
    hipLaunchKernelGGL(k_corr_up, dim3(3072), dim3(64), 0, stream, xref, xnb, bflow, bfeat, ws, bio);
    hipLaunchKernelGGL(k_conv0, dim3(256), dim3(256), 0, stream, inpT, wse + E_WT0, b0, hT);
    hipLaunchKernelGGL((k_conv32<2, 0>), dim3(256), dim3(256), 0, stream,
                       hT, wse + E_WT1, b1, t1T, (float*)nullptr, (const u16*)nullptr, bio);
    hipLaunchKernelGGL((k_conv32<2, 1>), dim3(256), dim3(256), 0, stream,
                       t1T, wse + E_WT2, b2, feaT, out, hT, bio);
    hipLaunchKernelGGL((k_conv32<1, 2>), dim3(256), dim3(256), 0, stream,
                       feaT, wse + E_WTF, bf, (u16*)nullptr, out, (const u16*)nullptr, bio);
  }
}

// Round 2
// 469.136 us; speedup vs baseline: 1.5545x; 1.1440x over previous
//
#include <hip/hip_runtime.h>

typedef unsigned short u16;
typedef unsigned int u32;
typedef __bf16 bf16x8 __attribute__((ext_vector_type(8)));
typedef float f32x4 __attribute__((ext_vector_type(4)));

#define HP 258
// weight-table element offsets within ws (u16 units)
#define E_WT0 0
#define E_WT1 37120
#define E_WT2 46592
#define E_WTF 56064
// per-batch tensor byte offsets within ws (ws >= 55.3 MB verified R6/R8)
#define OFF_INPT 131072ull
#define OFF_HT   17171456ull   // OFF_INPT + 258*258*128*2
#define OFF_T1   21431552ull   // OFF_HT + 258*258*32*2
#define OFF_FEA  25691648ull   // OFF_T1 + 258*258*32*2
#define OFF_XREFT 29951744ull  // [256][256][32] bf16 = 4,194,304 B
#define OFF_XNBT  34146048ull  // [264][272][32] bf16 (rows -4..259, px -4..267) = 4,595,712 B
#define WS_NEED   38741760ull

__device__ __forceinline__ float bf2f(u16 u){ u32 x = ((u32)u) << 16; return __builtin_bit_cast(float, x); }
__device__ __forceinline__ u16 f2bf(float f){
  u32 x = __builtin_bit_cast(u32, f);
  return (u16)((x + 0x7fffu + ((x >> 16) & 1u)) >> 16);   // RNE
}
__device__ __forceinline__ u32 pack2(float a, float b){ return (u32)f2bf(a) | ((u32)f2bf(b) << 16); }
__device__ __forceinline__ float lrelu(float x){ return x >= 0.f ? x : 0.1f * x; }

__global__ void k_sent(float* __restrict__ out, float val){
  if (threadIdx.x == 0 && blockIdx.x == 0) out[0] = val;
}

// ---------------- halo-ring zeroing for all four per-batch buffers (once per launch) ----------
__global__ __launch_bounds__(256) void k_halo(char* __restrict__ ws){
  int idx = blockIdx.x * 256 + threadIdx.x;
  if (idx >= 258 * 258) return;
  int y = idx / 258;
  int x = idx - y * 258;
  if (y != 0 && y != 257 && x != 0 && x != 257) return;
  uint4 z = make_uint4(0u, 0u, 0u, 0u);
  size_t pix = (size_t)idx;
  uint4* p0 = (uint4*)(ws + OFF_INPT + pix * 256);
  #pragma unroll
  for (int k = 0; k < 16; k++) p0[k] = z;
  uint4* p1 = (uint4*)(ws + OFF_HT + pix * 64);
  uint4* p2 = (uint4*)(ws + OFF_T1 + pix * 64);
  uint4* p3 = (uint4*)(ws + OFF_FEA + pix * 64);
  #pragma unroll
  for (int k = 0; k < 4; k++){ p1[k] = z; p2[k] = z; p3[k] = z; }
}

// ---------------- weight re-layout: Wt[co][tap*Cpad + c], tap-major K, channel-permuted -------
// inpT channel order: 0..31 up-feat, 32..33 flow, 34..114 corr(dy*9+dx), 115..127 zero.
// Original (R8-verified) w0 input-channel order: 0..80 corr, 81..112 feat, 113..114 flow.
__global__ __launch_bounds__(256) void k_wprep(const float* __restrict__ w0, const float* __restrict__ w1,
    const float* __restrict__ w2, const float* __restrict__ wf, u16* __restrict__ wse){
  for (int idx = blockIdx.x * 256 + threadIdx.x; idx < 60800; idx += 64 * 256){
    float v = 0.f;
    if (idx < 37120){                       // Wt0: 32 rows x 1160 (K=9*128=1152 used)
      int co = idx / 1160, kk = idx % 1160;
      if (kk < 1152){
        int tap = kk >> 7, c = kk & 127;
        if (c < 115){
          int oc = (c < 34) ? (81 + c) : (c - 34);
          v = w0[(co * 115 + oc) * 9 + tap];
        }
      }
    } else if (idx < 46592){                // Wt1: 32 x 296 (K=9*32=288)
      int r = idx - 37120; int co = r / 296, kk = r % 296;
      if (kk < 288){ int tap = kk >> 5, c = kk & 31; v = w1[(co * 32 + c) * 9 + tap]; }
    } else if (idx < 56064){                // Wt2
      int r = idx - 46592; int co = r / 296, kk = r % 296;
      if (kk < 288){ int tap = kk >> 5, c = kk & 31; v = w2[(co * 32 + c) * 9 + tap]; }
    } else {                                // Wtf: 16 x 296, rows 3..15 zero
      int r = idx - 56064; int co = r / 296, kk = r % 296;
      if (kk < 288 && co < 3){ int tap = kk >> 5, c = kk & 31; v = wf[(co * 32 + c) * 9 + tap]; }
    }
    wse[idx] = f2bf(v);
  }
}

// ---------------- transpose prepass: [c][h][w] fp32 -> [h][w][c] bf16 -------------------------
// blocks 0..255: xrefT row h (no pad). blocks 256..519: xnbT padded row hp (rows -4..259, px -4..267).
// Reads: per channel one coalesced row read (lane=px). Writes: 64B contiguous per px.
__global__ __launch_bounds__(320) void k_xpose(const float* __restrict__ xref,
    const float* __restrict__ xnb, u16* __restrict__ xrefT, u16* __restrict__ xnbT, int bio){
  const int t = threadIdx.x;
  const int bxx = blockIdx.x;
  float v[32];
  u32 p[16];
  if (bxx < 256){
    if (t >= 256) return;
    const float* src = xref + ((size_t)bio * 32) * 65536 + (size_t)bxx * 256 + t;
    #pragma unroll
    for (int c = 0; c < 32; c++) v[c] = src[(size_t)c * 65536];
    #pragma unroll
    for (int k = 0; k < 16; k++) p[k] = pack2(v[2 * k], v[2 * k + 1]);
    uint4* dst = (uint4*)(xrefT + ((size_t)bxx * 256 + t) * 32);
    #pragma unroll
    for (int q = 0; q < 4; q++) dst[q] = ((uint4*)p)[q];
  } else {
    if (t >= 272) return;
    const int hp = bxx - 256;
    const int ih = hp - 4, px = t - 4;
    uint4* dst = (uint4*)(xnbT + ((size_t)hp * 272 + t) * 32);
    if (ih >= 0 && ih <= 255 && px >= 0 && px <= 255){
      const float* src = xnb + ((size_t)bio * 32) * 65536 + (size_t)ih * 256 + px;
      #pragma unroll
      for (int c = 0; c < 32; c++) v[c] = src[(size_t)c * 65536];
      #pragma unroll
      for (int k = 0; k < 16; k++) p[k] = pack2(v[2 * k], v[2 * k + 1]);
      #pragma unroll
      for (int q = 0; q < 4; q++) dst[q] = ((uint4*)p)[q];
    } else {
      uint4 zz = make_uint4(0u, 0u, 0u, 0u);
      #pragma unroll
      for (int q = 0; q < 4; q++) dst[q] = zz;
    }
  }
}

// ---------------- bilinear 2x upsample (ch 0..33) + zero tail ch 115..127 ---------------------
// grid = 17 channel-pairs x 256 rows, 64 threads, 4 px/thread.
__global__ __launch_bounds__(64) void k_up(const float* __restrict__ bflow,
    const float* __restrict__ bfeat, char* __restrict__ ws, int bio){
  const int t = threadIdx.x;
  const int bx = blockIdx.x;
  const int cb = bx >> 8;                    // 0..16
  const int r = bx & 255;
  const int h = (r & 7) * 32 + (r >> 3);     // XCD swizzle
  const int c0 = 2 * cb;
  const float* pl0 = (c0 < 32) ? (bfeat + ((size_t)(bio * 32 + c0)) * 16384)
                               : (bflow + ((size_t)(bio * 2 + (c0 - 32))) * 16384);
  const float* pl1 = (c0 < 31) ? (bfeat + ((size_t)(bio * 32 + c0 + 1)) * 16384)
                               : (bflow + ((size_t)(bio * 2 + (c0 - 31))) * 16384);
  const float s0 = (c0 >= 32) ? 2.f : 1.f;
  const float s1 = (c0 + 1 >= 32) ? 2.f : 1.f;
  int y0 = (h >> 1) - 1 + (h & 1);
  float fy = (h & 1) ? 0.25f : 0.75f;
  int y0o = (y0 < 0 ? 0 : y0) * 128;
  int y1o = ((y0 + 1) > 127 ? 127 : (y0 + 1)) * 128;
  #pragma unroll
  for (int pp = 0; pp < 4; pp++){
    int w = 4 * t + pp;
    int x0 = (w >> 1) - 1 + (w & 1);
    float fx = (w & 1) ? 0.25f : 0.75f;
    int x0c = x0 < 0 ? 0 : x0;
    int x1c = (x0 + 1) > 127 ? 127 : (x0 + 1);
    float a00 = pl0[y0o + x0c], a01 = pl0[y0o + x1c];
    float a10 = pl0[y1o + x0c], a11 = pl0[y1o + x1c];
    float ar0 = a00 + fx * (a01 - a00), ar1 = a10 + fx * (a11 - a10);
    float va = (ar0 + fy * (ar1 - ar0)) * s0;
    float b00 = pl1[y0o + x0c], b01 = pl1[y0o + x1c];
    float b10 = pl1[y1o + x0c], b11 = pl1[y1o + x1c];
    float br0 = b00 + fx * (b01 - b00), br1 = b10 + fx * (b11 - b10);
    float vb = (br0 + fy * (br1 - br0)) * s1;
    char* pxb = ws + OFF_INPT + ((size_t)(h + 1) * 258 + (w + 1)) * 256;
    *(u32*)(pxb + 4 * cb) = pack2(va, vb);
    if (cb == 16){                           // zero ch 115..127 (bytes 230..255)
      *(u16*)(pxb + 230) = 0;
      #pragma unroll
      for (int k2 = 0; k2 < 6; k2++) *(u32*)(pxb + 232 + 4 * k2) = 0;
    }
  }
}

// ---------------- MFMA correlation: D[m][n] = sum_c ref[c][w0+m] * nb[c][ih][w0+n-4] ----------
// Per wave: 16 px, all 9 dy x 9 dx. A-frag loaded once (K=32 = all channels); per dy two B-frags
// (24-px shifted window) -> 2 MFMAs. Epilogue: predicated 2B stores, exactly-once per (px,ch).
// Fragment layout (verified via conv kernels): A/B row = lane&15, k = (lane>>4)*8+j;
// D col = lane&15 (B-row), D row = (lane>>4)*4+reg (A-row).
__global__ __launch_bounds__(256) void k_corr_mfma(const u16* __restrict__ xrefT,
    const u16* __restrict__ xnbT, char* __restrict__ ws){
  const int tid = threadIdx.x;
  const int wv = tid >> 6, l = tid & 63;
  const int bx = blockIdx.x;
  const int r = bx & 255, sub = bx >> 8;
  const int h = (r & 7) * 32 + (r >> 3);     // XCD swizzle: nbT row reuse stays on-XCD
  const int w0 = (sub * 4 + wv) * 16;
  const int m16 = l & 15, g = l >> 4;

  uint4 ua = *(const uint4*)(xrefT + ((size_t)h * 256 + w0 + m16) * 32 + g * 8);
  bf16x8 av = __builtin_bit_cast(bf16x8, ua);

  // dy=0: padded row index = h+dy; frag0 pad-px = w0+n (actual px w0+n-4); frag1 = +16 px.
  size_t bOff = ((size_t)h * 272 + w0 + m16) * 32 + g * 8;
  char* outLane = ws + OFF_INPT + ((size_t)(h + 1) * 258 + (w0 + 1)) * 256
                  + (size_t)(g * 4) * 256 + 68;
  const f32x4 z = {0.f, 0.f, 0.f, 0.f};
  #pragma unroll
  for (int dy = 0; dy < 9; dy++){
    uint4 ub0 = *(const uint4*)(xnbT + bOff);
    uint4 ub1 = *(const uint4*)(xnbT + bOff + 512);
    bOff += 8704;                            // next padded row (272*32)
    f32x4 d0 = __builtin_amdgcn_mfma_f32_16x16x32_bf16(av, __builtin_bit_cast(bf16x8, ub0), z, 0, 0, 0);
    f32x4 d1 = __builtin_amdgcn_mfma_f32_16x16x32_bf16(av, __builtin_bit_cast(bf16x8, ub1), z, 0, 0, 0);
    #pragma unroll
    for (int j = 0; j < 4; j++){
      int dxa = m16 - g * 4 - j;             // frag0: dx = n - m
      int dxb = dxa + 16;                    // frag1: dx = n + 16 - m
      bool va = (unsigned)dxa <= 8u;
      bool vb = (unsigned)dxb <= 8u;
      if (va | vb){
        float val = va ? d0[j] : d1[j];
        int dx = va ? dxa : dxb;
        float f = lrelu(val * 0.03125f);
        *(u16*)(outLane + j * 256 + (dy * 9 + dx) * 2) = f2bf(f);
      }
    }
  }
}

// ---------------- conv0: 128->32, MFMA implicit GEMM, weights LDS-chunked ---------------------
__global__ __launch_bounds__(256) void k_conv0(const u16* __restrict__ inT, const u16* __restrict__ wt,
    const float* __restrict__ bias, u16* __restrict__ outA){
  __shared__ __align__(16) u16 wl[32 * 648];
  const int tid = threadIdx.x;
  const int bx = blockIdx.x;
  const int row = (bx & 7) * 32 + (bx >> 3);
  const int wv = tid >> 6, ln = tid & 63, l15 = ln & 15, l4 = ln >> 4;
  f32x4 acc[4][2] = {};
  const u16* aB[4];
  #pragma unroll
  for (int i = 0; i < 4; i++)
    aB[i] = inT + (size_t)(row * HP + (wv * 64 + i * 16 + l15)) * 128 + l4 * 8;

  // chunk 0: taps 0..3 (512 k-elems/row)
  for (int i = tid; i < 2048; i += 256){
    int co = i >> 6, q = i & 63;
    ((uint4*)&wl[co * 648])[q] = *(const uint4*)&wt[co * 1160 + q * 8];
  }
  __syncthreads();
  #pragma unroll
  for (int tap = 0; tap < 4; tap++){
    const int ky = tap / 3, kx = tap % 3;
    #pragma unroll
    for (int s = 0; s < 4; s++){
      bf16x8 bv[2];
      #pragma unroll
      for (int j = 0; j < 2; j++){
        uint4 u = *(const uint4*)&wl[(j * 16 + l15) * 648 + tap * 128 + s * 32 + l4 * 8];
        bv[j] = __builtin_bit_cast(bf16x8, u);
      }
      #pragma unroll
      for (int i = 0; i < 4; i++){
        uint4 ua = *(const uint4*)(aB[i] + (ky * HP + kx) * 128 + s * 32);
        bf16x8 av = __builtin_bit_cast(bf16x8, ua);
        #pragma unroll
        for (int j = 0; j < 2; j++)
          acc[i][j] = __builtin_amdgcn_mfma_f32_16x16x32_bf16(av, bv[j], acc[i][j], 0, 0, 0);
      }
    }
  }
  __syncthreads();
  // chunk 1: taps 4..8 (640 k-elems/row)
  for (int i = tid; i < 2560; i += 256){
    int co = i / 80, q = i % 80;
    ((uint4*)&wl[co * 648])[q] = *(const uint4*)&wt[co * 1160 + 512 + q * 8];
  }
  __syncthreads();
  #pragma unroll
  for (int tap = 4; tap < 9; tap++){
    const int ky = tap / 3, kx = tap % 3;
    #pragma unroll
    for (int s = 0; s < 4; s++){
      bf16x8 bv[2];
      #pragma unroll
      for (int j = 0; j < 2; j++){
        uint4 u = *(const uint4*)&wl[(j * 16 + l15) * 648 + (tap - 4) * 128 + s * 32 + l4 * 8];
        bv[j] = __builtin_bit_cast(bf16x8, u);
      }
      #pragma unroll
      for (int i = 0; i < 4; i++){
        uint4 ua = *(const uint4*)(aB[i] + (ky * HP + kx) * 128 + s * 32);
        bf16x8 av = __builtin_bit_cast(bf16x8, ua);
        #pragma unroll
        for (int j = 0; j < 2; j++)
          acc[i][j] = __builtin_amdgcn_mfma_f32_16x16x32_bf16(av, bv[j], acc[i][j], 0, 0, 0);
      }
    }
  }
  // epilogue: bias + lrelu -> hT halo layout (bf16)
  #pragma unroll
  for (int i = 0; i < 4; i++){
    const int pxb = wv * 64 + i * 16 + l4 * 4;
    #pragma unroll
    for (int j = 0; j < 2; j++){
      const int co = j * 16 + l15;
      const float bs = bias[co];
      #pragma unroll
      for (int r = 0; r < 4; r++){
        const int px = pxb + r;
        float v = lrelu(acc[i][j][r] + bs);
        outA[(size_t)((row + 1) * HP + px + 1) * 32 + co] = f2bf(v);
      }
    }
  }
}

// ---------------- 32-cin convs (conv1/conv2/convf), MFMA -------------------------------------
// MODE 0: bias+lrelu -> halo outH (t1). MODE 1: +resid, lrelu -> halo outH (fea) AND fp32 out feats.
// MODE 2: flows (co 0,1) + sigmoid mask (co 2) -> fp32 out.
template<int NT, int MODE>
__global__ __launch_bounds__(256) void k_conv32(const u16* __restrict__ inT, const u16* __restrict__ wt,
    const float* __restrict__ bias, u16* __restrict__ outH, float* __restrict__ outF,
    const u16* __restrict__ resid, int bio){
  constexpr int NR = (NT == 2) ? 32 : 16;
  __shared__ __align__(16) u16 wl[NR * 296];
  const int tid = threadIdx.x;
  for (int i = tid; i < NR * 296 / 8; i += 256)
    ((uint4*)wl)[i] = ((const uint4*)wt)[i];
  __syncthreads();
  const int bx = blockIdx.x;
  const int row = (bx & 7) * 32 + (bx >> 3);
  const int wv = tid >> 6, ln = tid & 63, l15 = ln & 15, l4 = ln >> 4;
  f32x4 acc[4][NT] = {};
  const u16* aB[4];
  #pragma unroll
  for (int i = 0; i < 4; i++)
    aB[i] = inT + (size_t)(row * HP + (wv * 64 + i * 16 + l15)) * 32 + l4 * 8;
  #pragma unroll
  for (int ky = 0; ky < 3; ky++){
    #pragma unroll
    for (int kx = 0; kx < 3; kx++){
      const int tap = ky * 3 + kx;
      bf16x8 bv[NT];
      #pragma unroll
      for (int j = 0; j < NT; j++){
        uint4 u = *(const uint4*)&wl[(j * 16 + l15) * 296 + tap * 32 + l4 * 8];
        bv[j] = __builtin_bit_cast(bf16x8, u);
      }
      #pragma unroll
      for (int i = 0; i < 4; i++){
        uint4 ua = *(const uint4*)(aB[i] + (ky * HP + kx) * 32);
        bf16x8 av = __builtin_bit_cast(bf16x8, ua);
        #pragma unroll
        for (int j = 0; j < NT; j++)
          acc[i][j] = __builtin_amdgcn_mfma_f32_16x16x32_bf16(av, bv[j], acc[i][j], 0, 0, 0);
      }
    }
  }
  #pragma unroll
  for (int i = 0; i < 4; i++){
    const int pxb = wv * 64 + i * 16 + l4 * 4;
    #pragma unroll
    for (int j = 0; j < NT; j++){
      const int co = j * 16 + l15;
      float bs;
      if constexpr (MODE == 2) bs = (co < 3) ? bias[co] : 0.f;
      else bs = bias[co];
      #pragma unroll
      for (int r = 0; r < 4; r++){
        const int px = pxb + r;
        float v = acc[i][j][r] + bs;
        if constexpr (MODE == 0){
          v = lrelu(v);
          outH[(size_t)((row + 1) * HP + px + 1) * 32 + co] = f2bf(v);
        } else if constexpr (MODE == 1){
          float hres = bf2f(resid[(size_t)((row + 1) * HP + px + 1) * 32 + co]);
          v = lrelu(v + hres);
          outH[(size_t)((row + 1) * HP + px + 1) * 32 + co] = f2bf(v);                  // feaT
          outF[786432 + ((size_t)(bio * 32 + co)) * 65536 + (size_t)row * 256 + px] = v; // feats
        } else {
          if (co < 2)
            outF[((size_t)(bio * 2 + co)) * 65536 + (size_t)row * 256 + px] = v;        // flows
          else if (co == 2){
            float s = 1.f / (1.f + __expf(-v));
            outF[524288 + (size_t)bio * 65536 + (size_t)row * 256 + px] = s;            // mask
          }
        }
      }
    }
  }
}

extern "C" void kernel_launch(void* const* d_in, const int* in_sizes, int n_in,
                              void* d_out, int out_size, void* d_ws, size_t ws_size,
                              hipStream_t stream){
  float* out = (float*)d_out;

  // ---- runtime interface verification (kept from R6; encodes any mismatch into out[0]) ----
  static const int exp_sizes[12] = {8388608, 8388608, 131072, 2097152,
                                    33120, 32, 9216, 32, 9216, 32, 864, 3};
  float sent = 0.f;
  if (n_in != 12) sent = 1.0e6f;
  else if (out_size != 9175040) sent = 2.0e6f;
  else {
    for (int i = 0; i < 12; i++)
      if (in_sizes[i] != exp_sizes[i]){ sent = 3.0e6f * (1.0f + 0.01f * i); break; }
    if (sent == 0.f && ws_size < WS_NEED)
      sent = 16.0f * (float)(ws_size >> 20);
  }
  if (sent != 0.f){
    hipLaunchKernelGGL(k_sent, dim3(1), dim3(64), 0, stream, out, sent);
    return;
  }

  const float* xref  = (const float*)d_in[0];
  const float* xnb   = (const float*)d_in[1];
  const float* bflow = (const float*)d_in[2];
  const float* bfeat = (const float*)d_in[3];
  const float* w0 = (const float*)d_in[4];
  const float* b0 = (const float*)d_in[5];
  const float* w1 = (const float*)d_in[6];
  const float* b1 = (const float*)d_in[7];
  const float* w2 = (const float*)d_in[8];
  const float* b2 = (const float*)d_in[9];
  const float* wf = (const float*)d_in[10];
  const float* bf = (const float*)d_in[11];
  char* ws = (char*)d_ws;
  u16* wse   = (u16*)d_ws;
  u16* inpT  = (u16*)(ws + OFF_INPT);
  u16* hT    = (u16*)(ws + OFF_HT);
  u16* t1T   = (u16*)(ws + OFF_T1);
  u16* feaT  = (u16*)(ws + OFF_FEA);
  u16* xrefT = (u16*)(ws + OFF_XREFT);
  u16* xnbT  = (u16*)(ws + OFF_XNBT);

  hipLaunchKernelGGL(k_halo, dim3(261), dim3(256), 0, stream, ws);
  hipLaunchKernelGGL(k_wprep, dim3(64), dim3(256), 0, stream, w0, w1, w2, wf, wse);
  for (int bio = 0; bio < 4; bio++){
    hipLaunchKernelGGL(k_xpose, dim3(520), dim3(320), 0, stream, xref, xnb, xrefT, xnbT, bio);
    hipLaunchKernelGGL(k_up, dim3(4352), dim3(64), 0, stream, bflow, bfeat, ws, bio);
    hipLaunchKernelGGL(k_corr_mfma, dim3(1024), dim3(256), 0, stream, xrefT, xnbT, ws);
    hipLaunchKernelGGL(k_conv0, dim3(256), dim3(256), 0, stream, inpT, wse + E_WT0, b0, hT);
    hipLaunchKernelGGL((k_conv32<2, 0>), dim3(256), dim3(256), 0, stream,
                       hT, wse + E_WT1, b1, t1T, (float*)nullptr, (const u16*)nullptr, bio);
    hipLaunchKernelGGL((k_conv32<2, 1>), dim3(256), dim3(256), 0, stream,
                       t1T, wse + E_WT2, b2, feaT, out, hT, bio);
    hipLaunchKernelGGL((k_conv32<1, 2>), dim3(256), dim3(256), 0, stream,
                       feaT, wse + E_WTF, bf, (u16*)nullptr, out, (const u16*)nullptr, bio);
  }
}

// Round 4
// 416.439 us; speedup vs baseline: 1.7512x; 1.1265x over previous
//
#include <hip/hip_runtime.h>

typedef unsigned short u16;
typedef unsigned int u32;
typedef __bf16 bf16x8 __attribute__((ext_vector_type(8)));
typedef float f32x4 __attribute__((ext_vector_type(4)));

#define HP 258
// weight-table element offsets within ws (u16 units)
#define E_WT0 0
#define E_WT1 37120
#define E_WT2 46592
#define E_WTF 56064
// ---- per-batch strided layout (R12, corrected): all 4 batches resident simultaneously ----
// 258*258 = 66564 pixels (R3 bug: used 66558 -> overlapping buffers, absmax 0.549)
#define OFF_INPT  131072ull
#define S_INPT    17040384ull            // 66564*128*2
#define OFF_HT    68292608ull            // OFF_INPT + 4*S_INPT
#define S_H       4260096ull             // 66564*32*2
#define OFF_T1    85332992ull            // OFF_HT + 4*S_H
#define OFF_FEA   102373376ull           // OFF_T1 + 4*S_H
#define OFF_XREFT 119413760ull           // OFF_FEA + 4*S_H
#define S_XREF    4194304ull             // 256*256*32*2
#define OFF_XNBT  136190976ull           // OFF_XREFT + 4*S_XREF
#define S_XNB     4595712ull             // 264*272*32*2
#define WS_NEED   154573824ull           // OFF_XNBT + 4*S_XNB  (ws is 256 MiB per R2 fill evidence)
// u16-element strides
#define SE_INPT 8520192u
#define SE_H    2130048u
#define SE_XREF 2097152u
#define SE_XNB  2297856u

__device__ __forceinline__ float bf2f(u16 u){ u32 x = ((u32)u) << 16; return __builtin_bit_cast(float, x); }
__device__ __forceinline__ u16 f2bf(float f){
  u32 x = __builtin_bit_cast(u32, f);
  return (u16)((x + 0x7fffu + ((x >> 16) & 1u)) >> 16);   // RNE
}
__device__ __forceinline__ u32 pack2(float a, float b){ return (u32)f2bf(a) | ((u32)f2bf(b) << 16); }
__device__ __forceinline__ float lrelu(float x){ return x >= 0.f ? x : 0.1f * x; }

__global__ void k_sent(float* __restrict__ out, float val){
  if (threadIdx.x == 0 && blockIdx.x == 0) out[0] = val;
}

// ---------------- halo-ring zeroing for all four per-batch buffer sets (once per launch) ------
__global__ __launch_bounds__(256) void k_halo(char* __restrict__ ws){
  int idx = blockIdx.x * 256 + threadIdx.x;
  const int bio = blockIdx.y;
  if (idx >= 258 * 258) return;
  int y = idx / 258;
  int x = idx - y * 258;
  if (y != 0 && y != 257 && x != 0 && x != 257) return;
  uint4 z = make_uint4(0u, 0u, 0u, 0u);
  size_t pix = (size_t)idx;
  uint4* p0 = (uint4*)(ws + OFF_INPT + (size_t)bio * S_INPT + pix * 256);
  #pragma unroll
  for (int k = 0; k < 16; k++) p0[k] = z;
  uint4* p1 = (uint4*)(ws + OFF_HT  + (size_t)bio * S_H + pix * 64);
  uint4* p2 = (uint4*)(ws + OFF_T1  + (size_t)bio * S_H + pix * 64);
  uint4* p3 = (uint4*)(ws + OFF_FEA + (size_t)bio * S_H + pix * 64);
  #pragma unroll
  for (int k = 0; k < 4; k++){ p1[k] = z; p2[k] = z; p3[k] = z; }
}

// ---------------- weight re-layout: Wt[co][tap*Cpad + c], tap-major K, channel-permuted -------
// inpT channel order: 0..31 up-feat, 32..33 flow, 34..114 corr(dy*9+dx), 115..127 zero.
// Original (R8-verified) w0 input-channel order: 0..80 corr, 81..112 feat, 113..114 flow.
__global__ __launch_bounds__(256) void k_wprep(const float* __restrict__ w0, const float* __restrict__ w1,
    const float* __restrict__ w2, const float* __restrict__ wf, u16* __restrict__ wse){
  for (int idx = blockIdx.x * 256 + threadIdx.x; idx < 60800; idx += 64 * 256){
    float v = 0.f;
    if (idx < 37120){                       // Wt0: 32 rows x 1160 (K=9*128=1152 used)
      int co = idx / 1160, kk = idx % 1160;
      if (kk < 1152){
        int tap = kk >> 7, c = kk & 127;
        if (c < 115){
          int oc = (c < 34) ? (81 + c) : (c - 34);
          v = w0[(co * 115 + oc) * 9 + tap];
        }
      }
    } else if (idx < 46592){                // Wt1: 32 x 296 (K=9*32=288)
      int r = idx - 37120; int co = r / 296, kk = r % 296;
      if (kk < 288){ int tap = kk >> 5, c = kk & 31; v = w1[(co * 32 + c) * 9 + tap]; }
    } else if (idx < 56064){                // Wt2
      int r = idx - 46592; int co = r / 296, kk = r % 296;
      if (kk < 288){ int tap = kk >> 5, c = kk & 31; v = w2[(co * 32 + c) * 9 + tap]; }
    } else {                                // Wtf: 16 x 296, rows 3..15 zero
      int r = idx - 56064; int co = r / 296, kk = r % 296;
      if (kk < 288 && co < 3){ int tap = kk >> 5, c = kk & 31; v = wf[(co * 32 + c) * 9 + tap]; }
    }
    wse[idx] = f2bf(v);
  }
}

// ---------------- transpose prepass: [c][h][w] fp32 -> [h][w][c] bf16 -------------------------
// blocks 0..255: xrefT row h (no pad). blocks 256..519: xnbT padded row hp (rows -4..259, px -4..267).
__global__ __launch_bounds__(320) void k_xpose(const float* __restrict__ xref,
    const float* __restrict__ xnb, u16* __restrict__ xrefT0, u16* __restrict__ xnbT0){
  const int t = threadIdx.x;
  const int bxx = blockIdx.x;
  const int bio = blockIdx.y;
  u16* xrefT = xrefT0 + (size_t)bio * SE_XREF;
  u16* xnbT  = xnbT0  + (size_t)bio * SE_XNB;
  float v[32];
  u32 p[16];
  if (bxx < 256){
    if (t >= 256) return;
    const float* src = xref + ((size_t)bio * 32) * 65536 + (size_t)bxx * 256 + t;
    #pragma unroll
    for (int c = 0; c < 32; c++) v[c] = src[(size_t)c * 65536];
    #pragma unroll
    for (int k = 0; k < 16; k++) p[k] = pack2(v[2 * k], v[2 * k + 1]);
    uint4* dst = (uint4*)(xrefT + ((size_t)bxx * 256 + t) * 32);
    #pragma unroll
    for (int q = 0; q < 4; q++) dst[q] = ((uint4*)p)[q];
  } else {
    if (t >= 272) return;
    const int hp = bxx - 256;
    const int ih = hp - 4, px = t - 4;
    uint4* dst = (uint4*)(xnbT + ((size_t)hp * 272 + t) * 32);
    if (ih >= 0 && ih <= 255 && px >= 0 && px <= 255){
      const float* src = xnb + ((size_t)bio * 32) * 65536 + (size_t)ih * 256 + px;
      #pragma unroll
      for (int c = 0; c < 32; c++) v[c] = src[(size_t)c * 65536];
      #pragma unroll
      for (int k = 0; k < 16; k++) p[k] = pack2(v[2 * k], v[2 * k + 1]);
      #pragma unroll
      for (int q = 0; q < 4; q++) dst[q] = ((uint4*)p)[q];
    } else {
      uint4 zz = make_uint4(0u, 0u, 0u, 0u);
      #pragma unroll
      for (int q = 0; q < 4; q++) dst[q] = zz;
    }
  }
}

// ---------------- bilinear 2x upsample (ch 0..33) + zero tail ch 115..127 ---------------------
// grid = (17 channel-pairs x 256 rows, 4 batches), 64 threads, 4 px/thread.
__global__ __launch_bounds__(64) void k_up(const float* __restrict__ bflow,
    const float* __restrict__ bfeat, char* __restrict__ ws){
  const int t = threadIdx.x;
  const int bx = blockIdx.x;
  const int bio = blockIdx.y;
  const int cb = bx >> 8;                    // 0..16
  const int r = bx & 255;
  const int h = (r & 7) * 32 + (r >> 3);     // XCD swizzle
  const int c0 = 2 * cb;
  const float* pl0 = (c0 < 32) ? (bfeat + ((size_t)(bio * 32 + c0)) * 16384)
                               : (bflow + ((size_t)(bio * 2 + (c0 - 32))) * 16384);
  const float* pl1 = (c0 < 31) ? (bfeat + ((size_t)(bio * 32 + c0 + 1)) * 16384)
                               : (bflow + ((size_t)(bio * 2 + (c0 - 31))) * 16384);
  const float s0 = (c0 >= 32) ? 2.f : 1.f;
  const float s1 = (c0 + 1 >= 32) ? 2.f : 1.f;
  int y0 = (h >> 1) - 1 + (h & 1);
  float fy = (h & 1) ? 0.25f : 0.75f;
  int y0o = (y0 < 0 ? 0 : y0) * 128;
  int y1o = ((y0 + 1) > 127 ? 127 : (y0 + 1)) * 128;
  char* base = ws + OFF_INPT + (size_t)bio * S_INPT;
  #pragma unroll
  for (int pp = 0; pp < 4; pp++){
    int w = 4 * t + pp;
    int x0 = (w >> 1) - 1 + (w & 1);
    float fx = (w & 1) ? 0.25f : 0.75f;
    int x0c = x0 < 0 ? 0 : x0;
    int x1c = (x0 + 1) > 127 ? 127 : (x0 + 1);
    float a00 = pl0[y0o + x0c], a01 = pl0[y0o + x1c];
    float a10 = pl0[y1o + x0c], a11 = pl0[y1o + x1c];
    float ar0 = a00 + fx * (a01 - a00), ar1 = a10 + fx * (a11 - a10);
    float va = (ar0 + fy * (ar1 - ar0)) * s0;
    float b00 = pl1[y0o + x0c], b01 = pl1[y0o + x1c];
    float b10 = pl1[y1o + x0c], b11 = pl1[y1o + x1c];
    float br0 = b00 + fx * (b01 - b00), br1 = b10 + fx * (b11 - b10);
    float vb = (br0 + fy * (br1 - br0)) * s1;
    char* pxb = base + ((size_t)(h + 1) * 258 + (w + 1)) * 256;
    *(u32*)(pxb + 4 * cb) = pack2(va, vb);
    if (cb == 16){                           // zero ch 115..127 (bytes 230..255)
      *(u16*)(pxb + 230) = 0;
      #pragma unroll
      for (int k2 = 0; k2 < 6; k2++) *(u32*)(pxb + 232 + 4 * k2) = 0;
    }
  }
}

// ---------------- MFMA correlation: D[m][n] = sum_c ref[c][w0+m] * nb[c][ih][w0+n-4] ----------
// Per wave: 16 px, all 9 dy x 9 dx. A-frag loaded once (K=32 = all channels); per dy two B-frags
// (24-px shifted window) -> 2 MFMAs. Epilogue: predicated 2B stores, exactly-once per (px,ch).
// Fragment layout (verified via conv kernels): A/B row = lane&15, k = (lane>>4)*8+j;
// D col = lane&15 (B-row), D row = (lane>>4)*4+reg (A-row).
__global__ __launch_bounds__(256) void k_corr_mfma(const u16* __restrict__ xrefT0,
    const u16* __restrict__ xnbT0, char* __restrict__ ws){
  const int tid = threadIdx.x;
  const int wv = tid >> 6, l = tid & 63;
  const int bx = blockIdx.x;
  const int bio = blockIdx.y;
  const u16* xrefT = xrefT0 + (size_t)bio * SE_XREF;
  const u16* xnbT  = xnbT0  + (size_t)bio * SE_XNB;
  const int r = bx & 255, sub = bx >> 8;
  const int h = (r & 7) * 32 + (r >> 3);     // XCD swizzle: nbT row reuse stays on-XCD
  const int w0 = (sub * 4 + wv) * 16;
  const int m16 = l & 15, g = l >> 4;

  uint4 ua = *(const uint4*)(xrefT + ((size_t)h * 256 + w0 + m16) * 32 + g * 8);
  bf16x8 av = __builtin_bit_cast(bf16x8, ua);

  size_t bOff = ((size_t)h * 272 + w0 + m16) * 32 + g * 8;
  char* outLane = ws + OFF_INPT + (size_t)bio * S_INPT
                  + ((size_t)(h + 1) * 258 + (w0 + 1)) * 256
                  + (size_t)(g * 4) * 256 + 68;
  const f32x4 z = {0.f, 0.f, 0.f, 0.f};
  #pragma unroll
  for (int dy = 0; dy < 9; dy++){
    uint4 ub0 = *(const uint4*)(xnbT + bOff);
    uint4 ub1 = *(const uint4*)(xnbT + bOff + 512);
    bOff += 8704;                            // next padded row (272*32)
    f32x4 d0 = __builtin_amdgcn_mfma_f32_16x16x32_bf16(av, __builtin_bit_cast(bf16x8, ub0), z, 0, 0, 0);
    f32x4 d1 = __builtin_amdgcn_mfma_f32_16x16x32_bf16(av, __builtin_bit_cast(bf16x8, ub1), z, 0, 0, 0);
    #pragma unroll
    for (int j = 0; j < 4; j++){
      int dxa = m16 - g * 4 - j;             // frag0: dx = n - m
      int dxb = dxa + 16;                    // frag1: dx = n + 16 - m
      bool va = (unsigned)dxa <= 8u;
      bool vb = (unsigned)dxb <= 8u;
      if (va | vb){
        float val = va ? d0[j] : d1[j];
        int dx = va ? dxa : dxb;
        float f = lrelu(val * 0.03125f);
        *(u16*)(outLane + j * 256 + (dy * 9 + dx) * 2) = f2bf(f);
      }
    }
  }
}

// ---------------- conv0: 128->32, MFMA implicit GEMM, weights LDS-chunked ---------------------
__global__ __launch_bounds__(256) void k_conv0(const u16* __restrict__ inT0, const u16* __restrict__ wt,
    const float* __restrict__ bias, u16* __restrict__ outA0){
  __shared__ __align__(16) u16 wl[32 * 648];
  const int tid = threadIdx.x;
  const int bx = blockIdx.x;
  const int bio = blockIdx.y;
  const u16* inT = inT0 + (size_t)bio * SE_INPT;
  u16* outA = outA0 + (size_t)bio * SE_H;
  const int row = (bx & 7) * 32 + (bx >> 3);
  const int wv = tid >> 6, ln = tid & 63, l15 = ln & 15, l4 = ln >> 4;
  f32x4 acc[4][2] = {};
  const u16* aB[4];
  #pragma unroll
  for (int i = 0; i < 4; i++)
    aB[i] = inT + (size_t)(row * HP + (wv * 64 + i * 16 + l15)) * 128 + l4 * 8;

  // chunk 0: taps 0..3 (512 k-elems/row)
  for (int i = tid; i < 2048; i += 256){
    int co = i >> 6, q = i & 63;
    ((uint4*)&wl[co * 648])[q] = *(const uint4*)&wt[co * 1160 + q * 8];
  }
  __syncthreads();
  #pragma unroll
  for (int tap = 0; tap < 4; tap++){
    const int ky = tap / 3, kx = tap % 3;
    #pragma unroll
    for (int s = 0; s < 4; s++){
      bf16x8 bv[2];
      #pragma unroll
      for (int j = 0; j < 2; j++){
        uint4 u = *(const uint4*)&wl[(j * 16 + l15) * 648 + tap * 128 + s * 32 + l4 * 8];
        bv[j] = __builtin_bit_cast(bf16x8, u);
      }
      #pragma unroll
      for (int i = 0; i < 4; i++){
        uint4 ua = *(const uint4*)(aB[i] + (ky * HP + kx) * 128 + s * 32);
        bf16x8 av = __builtin_bit_cast(bf16x8, ua);
        #pragma unroll
        for (int j = 0; j < 2; j++)
          acc[i][j] = __builtin_amdgcn_mfma_f32_16x16x32_bf16(av, bv[j], acc[i][j], 0, 0, 0);
      }
    }
  }
  __syncthreads();
  // chunk 1: taps 4..8 (640 k-elems/row)
  for (int i = tid; i < 2560; i += 256){
    int co = i / 80, q = i % 80;
    ((uint4*)&wl[co * 648])[q] = *(const uint4*)&wt[co * 1160 + 512 + q * 8];
  }
  __syncthreads();
  #pragma unroll
  for (int tap = 4; tap < 9; tap++){
    const int ky = tap / 3, kx = tap % 3;
    #pragma unroll
    for (int s = 0; s < 4; s++){
      bf16x8 bv[2];
      #pragma unroll
      for (int j = 0; j < 2; j++){
        uint4 u = *(const uint4*)&wl[(j * 16 + l15) * 648 + (tap - 4) * 128 + s * 32 + l4 * 8];
        bv[j] = __builtin_bit_cast(bf16x8, u);
      }
      #pragma unroll
      for (int i = 0; i < 4; i++){
        uint4 ua = *(const uint4*)(aB[i] + (ky * HP + kx) * 128 + s * 32);
        bf16x8 av = __builtin_bit_cast(bf16x8, ua);
        #pragma unroll
        for (int j = 0; j < 2; j++)
          acc[i][j] = __builtin_amdgcn_mfma_f32_16x16x32_bf16(av, bv[j], acc[i][j], 0, 0, 0);
      }
    }
  }
  // epilogue: bias + lrelu -> hT halo layout (bf16)
  #pragma unroll
  for (int i = 0; i < 4; i++){
    const int pxb = wv * 64 + i * 16 + l4 * 4;
    #pragma unroll
    for (int j = 0; j < 2; j++){
      const int co = j * 16 + l15;
      const float bs = bias[co];
      #pragma unroll
      for (int r = 0; r < 4; r++){
        const int px = pxb + r;
        float v = lrelu(acc[i][j][r] + bs);
        outA[(size_t)((row + 1) * HP + px + 1) * 32 + co] = f2bf(v);
      }
    }
  }
}

// ---------------- 32-cin convs (conv1/conv2/convf), MFMA -------------------------------------
// MODE 0: bias+lrelu -> halo outH (t1). MODE 1: +resid, lrelu -> halo outH (fea) AND fp32 out feats.
// MODE 2: flows (co 0,1) + sigmoid mask (co 2) -> fp32 out.
template<int NT, int MODE>
__global__ __launch_bounds__(256) void k_conv32(const u16* __restrict__ inT0, const u16* __restrict__ wt,
    const float* __restrict__ bias, u16* __restrict__ outH0, float* __restrict__ outF,
    const u16* __restrict__ resid0){
  constexpr int NR = (NT == 2) ? 32 : 16;
  __shared__ __align__(16) u16 wl[NR * 296];
  const int tid = threadIdx.x;
  const int bio = blockIdx.y;
  const u16* inT = inT0 + (size_t)bio * SE_H;
  for (int i = tid; i < NR * 296 / 8; i += 256)
    ((uint4*)wl)[i] = ((const uint4*)wt)[i];
  __syncthreads();
  const int bx = blockIdx.x;
  const int row = (bx & 7) * 32 + (bx >> 3);
  const int wv = tid >> 6, ln = tid & 63, l15 = ln & 15, l4 = ln >> 4;
  f32x4 acc[4][NT] = {};
  const u16* aB[4];
  #pragma unroll
  for (int i = 0; i < 4; i++)
    aB[i] = inT + (size_t)(row * HP + (wv * 64 + i * 16 + l15)) * 32 + l4 * 8;
  #pragma unroll
  for (int ky = 0; ky < 3; ky++){
    #pragma unroll
    for (int kx = 0; kx < 3; kx++){
      const int tap = ky * 3 + kx;
      bf16x8 bv[NT];
      #pragma unroll
      for (int j = 0; j < NT; j++){
        uint4 u = *(const uint4*)&wl[(j * 16 + l15) * 296 + tap * 32 + l4 * 8];
        bv[j] = __builtin_bit_cast(bf16x8, u);
      }
      #pragma unroll
      for (int i = 0; i < 4; i++){
        uint4 ua = *(const uint4*)(aB[i] + (ky * HP + kx) * 32);
        bf16x8 av = __builtin_bit_cast(bf16x8, ua);
        #pragma unroll
        for (int j = 0; j < NT; j++)
          acc[i][j] = __builtin_amdgcn_mfma_f32_16x16x32_bf16(av, bv[j], acc[i][j], 0, 0, 0);
      }
    }
  }
  #pragma unroll
  for (int i = 0; i < 4; i++){
    const int pxb = wv * 64 + i * 16 + l4 * 4;
    #pragma unroll
    for (int j = 0; j < NT; j++){
      const int co = j * 16 + l15;
      float bs;
      if constexpr (MODE == 2) bs = (co < 3) ? bias[co] : 0.f;
      else bs = bias[co];
      #pragma unroll
      for (int r = 0; r < 4; r++){
        const int px = pxb + r;
        float v = acc[i][j][r] + bs;
        if constexpr (MODE == 0){
          v = lrelu(v);
          outH0[(size_t)bio * SE_H + (size_t)((row + 1) * HP + px + 1) * 32 + co] = f2bf(v);
        } else if constexpr (MODE == 1){
          float hres = bf2f(resid0[(size_t)bio * SE_H + (size_t)((row + 1) * HP + px + 1) * 32 + co]);
          v = lrelu(v + hres);
          outH0[(size_t)bio * SE_H + (size_t)((row + 1) * HP + px + 1) * 32 + co] = f2bf(v); // feaT
          outF[786432 + ((size_t)(bio * 32 + co)) * 65536 + (size_t)row * 256 + px] = v;     // feats
        } else {
          if (co < 2)
            outF[((size_t)(bio * 2 + co)) * 65536 + (size_t)row * 256 + px] = v;             // flows
          else if (co == 2){
            float s = 1.f / (1.f + __expf(-v));
            outF[524288 + (size_t)bio * 65536 + (size_t)row * 256 + px] = s;                 // mask
          }
        }
      }
    }
  }
}

extern "C" void kernel_launch(void* const* d_in, const int* in_sizes, int n_in,
                              void* d_out, int out_size, void* d_ws, size_t ws_size,
                              hipStream_t stream){
  float* out = (float*)d_out;

  // ---- runtime interface verification (kept from R6; encodes any mismatch into out[0]) ----
  static const int exp_sizes[12] = {8388608, 8388608, 131072, 2097152,
                                    33120, 32, 9216, 32, 9216, 32, 864, 3};
  float sent = 0.f;
  if (n_in != 12) sent = 1.0e6f;
  else if (out_size != 9175040) sent = 2.0e6f;
  else {
    for (int i = 0; i < 12; i++)
      if (in_sizes[i] != exp_sizes[i]){ sent = 3.0e6f * (1.0f + 0.01f * i); break; }
    if (sent == 0.f && ws_size < WS_NEED)
      sent = 16.0f * (float)(ws_size >> 20);
  }
  if (sent != 0.f){
    hipLaunchKernelGGL(k_sent, dim3(1), dim3(64), 0, stream, out, sent);
    return;
  }

  const float* xref  = (const float*)d_in[0];
  const float* xnb   = (const float*)d_in[1];
  const float* bflow = (const float*)d_in[2];
  const float* bfeat = (const float*)d_in[3];
  const float* w0 = (const float*)d_in[4];
  const float* b0 = (const float*)d_in[5];
  const float* w1 = (const float*)d_in[6];
  const float* b1 = (const float*)d_in[7];
  const float* w2 = (const float*)d_in[8];
  const float* b2 = (const float*)d_in[9];
  const float* wf = (const float*)d_in[10];
  const float* bf = (const float*)d_in[11];
  char* ws = (char*)d_ws;
  u16* wse   = (u16*)d_ws;
  u16* inpT  = (u16*)(ws + OFF_INPT);
  u16* hT    = (u16*)(ws + OFF_HT);
  u16* t1T   = (u16*)(ws + OFF_T1);
  u16* feaT  = (u16*)(ws + OFF_FEA);
  u16* xrefT = (u16*)(ws + OFF_XREFT);
  u16* xnbT  = (u16*)(ws + OFF_XNBT);

  hipLaunchKernelGGL(k_halo, dim3(261, 4), dim3(256), 0, stream, ws);
  hipLaunchKernelGGL(k_wprep, dim3(64), dim3(256), 0, stream, w0, w1, w2, wf, wse);
  hipLaunchKernelGGL(k_xpose, dim3(520, 4), dim3(320), 0, stream, xref, xnb, xrefT, xnbT);
  hipLaunchKernelGGL(k_up, dim3(4352, 4), dim3(64), 0, stream, bflow, bfeat, ws);
  hipLaunchKernelGGL(k_corr_mfma, dim3(1024, 4), dim3(256), 0, stream, xrefT, xnbT, ws);
  hipLaunchKernelGGL(k_conv0, dim3(256, 4), dim3(256), 0, stream, inpT, wse + E_WT0, b0, hT);
  hipLaunchKernelGGL((k_conv32<2, 0>), dim3(256, 4), dim3(256), 0, stream,
                     hT, wse + E_WT1, b1, t1T, (float*)nullptr, (const u16*)nullptr);
  hipLaunchKernelGGL((k_conv32<2, 1>), dim3(256, 4), dim3(256), 0, stream,
                     t1T, wse + E_WT2, b2, feaT, out, hT);
  hipLaunchKernelGGL((k_conv32<1, 2>), dim3(256, 4), dim3(256), 0, stream,
                     feaT, wse + E_WTF, bf, (u16*)nullptr, out, (const u16*)nullptr);
}

// Round 5
// 406.689 us; speedup vs baseline: 1.7932x; 1.0240x over previous
//
#include <hip/hip_runtime.h>

typedef unsigned short u16;
typedef unsigned int u32;
typedef __bf16 bf16x8 __attribute__((ext_vector_type(8)));
typedef float f32x4 __attribute__((ext_vector_type(4)));

#define HP 258
// weight-table element offsets within ws (u16 units)
#define E_WT0 0
#define E_WT1 37120
#define E_WT2 46592
#define E_WTF 56064
// ---- per-batch strided layout (R12, corrected): all 4 batches resident simultaneously ----
// 258*258 = 66564 pixels (R3 bug: used 66558 -> overlapping buffers, absmax 0.549)
#define OFF_INPT  131072ull
#define S_INPT    17040384ull            // 66564*128*2
#define OFF_HT    68292608ull            // OFF_INPT + 4*S_INPT
#define S_H       4260096ull             // 66564*32*2
#define OFF_T1    85332992ull            // OFF_HT + 4*S_H
#define OFF_FEA   102373376ull           // OFF_T1 + 4*S_H
#define OFF_XREFT 119413760ull           // OFF_FEA + 4*S_H
#define S_XREF    4194304ull             // 256*256*32*2
#define OFF_XNBT  136190976ull           // OFF_XREFT + 4*S_XREF
#define S_XNB     4595712ull             // 264*272*32*2
#define WS_NEED   154573824ull           // OFF_XNBT + 4*S_XNB  (ws is 256 MiB per R2 fill evidence)
// u16-element strides
#define SE_INPT 8520192u
#define SE_H    2130048u
#define SE_XREF 2097152u
#define SE_XNB  2297856u

__device__ __forceinline__ float bf2f(u16 u){ u32 x = ((u32)u) << 16; return __builtin_bit_cast(float, x); }
__device__ __forceinline__ u16 f2bf(float f){
  u32 x = __builtin_bit_cast(u32, f);
  return (u16)((x + 0x7fffu + ((x >> 16) & 1u)) >> 16);   // RNE
}
__device__ __forceinline__ u32 pack2(float a, float b){ return (u32)f2bf(a) | ((u32)f2bf(b) << 16); }
__device__ __forceinline__ float lrelu(float x){ return x >= 0.f ? x : 0.1f * x; }

__global__ void k_sent(float* __restrict__ out, float val){
  if (threadIdx.x == 0 && blockIdx.x == 0) out[0] = val;
}

// ---------------- halo-ring zeroing for all four per-batch buffer sets (once per launch) ------
__global__ __launch_bounds__(256) void k_halo(char* __restrict__ ws){
  int idx = blockIdx.x * 256 + threadIdx.x;
  const int bio = blockIdx.y;
  if (idx >= 258 * 258) return;
  int y = idx / 258;
  int x = idx - y * 258;
  if (y != 0 && y != 257 && x != 0 && x != 257) return;
  uint4 z = make_uint4(0u, 0u, 0u, 0u);
  size_t pix = (size_t)idx;
  uint4* p0 = (uint4*)(ws + OFF_INPT + (size_t)bio * S_INPT + pix * 256);
  #pragma unroll
  for (int k = 0; k < 16; k++) p0[k] = z;
  uint4* p1 = (uint4*)(ws + OFF_HT  + (size_t)bio * S_H + pix * 64);
  uint4* p2 = (uint4*)(ws + OFF_T1  + (size_t)bio * S_H + pix * 64);
  uint4* p3 = (uint4*)(ws + OFF_FEA + (size_t)bio * S_H + pix * 64);
  #pragma unroll
  for (int k = 0; k < 4; k++){ p1[k] = z; p2[k] = z; p3[k] = z; }
}

// ---------------- weight re-layout: Wt[co][tap*Cpad + c], tap-major K, channel-permuted -------
// inpT channel order: 0..31 up-feat, 32..33 flow, 34..114 corr(dy*9+dx), 115..127 zero.
// Original (R8-verified) w0 input-channel order: 0..80 corr, 81..112 feat, 113..114 flow.
__global__ __launch_bounds__(256) void k_wprep(const float* __restrict__ w0, const float* __restrict__ w1,
    const float* __restrict__ w2, const float* __restrict__ wf, u16* __restrict__ wse){
  for (int idx = blockIdx.x * 256 + threadIdx.x; idx < 60800; idx += 64 * 256){
    float v = 0.f;
    if (idx < 37120){                       // Wt0: 32 rows x 1160 (K=9*128=1152 used)
      int co = idx / 1160, kk = idx % 1160;
      if (kk < 1152){
        int tap = kk >> 7, c = kk & 127;
        if (c < 115){
          int oc = (c < 34) ? (81 + c) : (c - 34);
          v = w0[(co * 115 + oc) * 9 + tap];
        }
      }
    } else if (idx < 46592){                // Wt1: 32 x 296 (K=9*32=288)
      int r = idx - 37120; int co = r / 296, kk = r % 296;
      if (kk < 288){ int tap = kk >> 5, c = kk & 31; v = w1[(co * 32 + c) * 9 + tap]; }
    } else if (idx < 56064){                // Wt2
      int r = idx - 46592; int co = r / 296, kk = r % 296;
      if (kk < 288){ int tap = kk >> 5, c = kk & 31; v = w2[(co * 32 + c) * 9 + tap]; }
    } else {                                // Wtf: 16 x 296, rows 3..15 zero
      int r = idx - 56064; int co = r / 296, kk = r % 296;
      if (kk < 288 && co < 3){ int tap = kk >> 5, c = kk & 31; v = wf[(co * 32 + c) * 9 + tap]; }
    }
    wse[idx] = f2bf(v);
  }
}

// ---------------- transpose prepass: [c][h][w] fp32 -> [h][w][c] bf16 -------------------------
// blocks 0..255: xrefT row h (no pad). blocks 256..519: xnbT padded row hp (rows -4..259, px -4..267).
__global__ __launch_bounds__(320) void k_xpose(const float* __restrict__ xref,
    const float* __restrict__ xnb, u16* __restrict__ xrefT0, u16* __restrict__ xnbT0){
  const int t = threadIdx.x;
  const int bxx = blockIdx.x;
  const int bio = blockIdx.y;
  u16* xrefT = xrefT0 + (size_t)bio * SE_XREF;
  u16* xnbT  = xnbT0  + (size_t)bio * SE_XNB;
  float v[32];
  u32 p[16];
  if (bxx < 256){
    if (t >= 256) return;
    const float* src = xref + ((size_t)bio * 32) * 65536 + (size_t)bxx * 256 + t;
    #pragma unroll
    for (int c = 0; c < 32; c++) v[c] = src[(size_t)c * 65536];
    #pragma unroll
    for (int k = 0; k < 16; k++) p[k] = pack2(v[2 * k], v[2 * k + 1]);
    uint4* dst = (uint4*)(xrefT + ((size_t)bxx * 256 + t) * 32);
    #pragma unroll
    for (int q = 0; q < 4; q++) dst[q] = ((uint4*)p)[q];
  } else {
    if (t >= 272) return;
    const int hp = bxx - 256;
    const int ih = hp - 4, px = t - 4;
    uint4* dst = (uint4*)(xnbT + ((size_t)hp * 272 + t) * 32);
    if (ih >= 0 && ih <= 255 && px >= 0 && px <= 255){
      const float* src = xnb + ((size_t)bio * 32) * 65536 + (size_t)ih * 256 + px;
      #pragma unroll
      for (int c = 0; c < 32; c++) v[c] = src[(size_t)c * 65536];
      #pragma unroll
      for (int k = 0; k < 16; k++) p[k] = pack2(v[2 * k], v[2 * k + 1]);
      #pragma unroll
      for (int q = 0; q < 4; q++) dst[q] = ((uint4*)p)[q];
    } else {
      uint4 zz = make_uint4(0u, 0u, 0u, 0u);
      #pragma unroll
      for (int q = 0; q < 4; q++) dst[q] = zz;
    }
  }
}

// ---------------- bilinear 2x upsample (ch 0..33) + zero tail ch 115..127 ---------------------
// grid = (17 channel-pairs x 256 rows, 4 batches), 64 threads, 4 px/thread.
__global__ __launch_bounds__(64) void k_up(const float* __restrict__ bflow,
    const float* __restrict__ bfeat, char* __restrict__ ws){
  const int t = threadIdx.x;
  const int bx = blockIdx.x;
  const int bio = blockIdx.y;
  const int cb = bx >> 8;                    // 0..16
  const int r = bx & 255;
  const int h = (r & 7) * 32 + (r >> 3);     // XCD swizzle
  const int c0 = 2 * cb;
  const float* pl0 = (c0 < 32) ? (bfeat + ((size_t)(bio * 32 + c0)) * 16384)
                               : (bflow + ((size_t)(bio * 2 + (c0 - 32))) * 16384);
  const float* pl1 = (c0 < 31) ? (bfeat + ((size_t)(bio * 32 + c0 + 1)) * 16384)
                               : (bflow + ((size_t)(bio * 2 + (c0 - 31))) * 16384);
  const float s0 = (c0 >= 32) ? 2.f : 1.f;
  const float s1 = (c0 + 1 >= 32) ? 2.f : 1.f;
  int y0 = (h >> 1) - 1 + (h & 1);
  float fy = (h & 1) ? 0.25f : 0.75f;
  int y0o = (y0 < 0 ? 0 : y0) * 128;
  int y1o = ((y0 + 1) > 127 ? 127 : (y0 + 1)) * 128;
  char* base = ws + OFF_INPT + (size_t)bio * S_INPT;
  #pragma unroll
  for (int pp = 0; pp < 4; pp++){
    int w = 4 * t + pp;
    int x0 = (w >> 1) - 1 + (w & 1);
    float fx = (w & 1) ? 0.25f : 0.75f;
    int x0c = x0 < 0 ? 0 : x0;
    int x1c = (x0 + 1) > 127 ? 127 : (x0 + 1);
    float a00 = pl0[y0o + x0c], a01 = pl0[y0o + x1c];
    float a10 = pl0[y1o + x0c], a11 = pl0[y1o + x1c];
    float ar0 = a00 + fx * (a01 - a00), ar1 = a10 + fx * (a11 - a10);
    float va = (ar0 + fy * (ar1 - ar0)) * s0;
    float b00 = pl1[y0o + x0c], b01 = pl1[y0o + x1c];
    float b10 = pl1[y1o + x0c], b11 = pl1[y1o + x1c];
    float br0 = b00 + fx * (b01 - b00), br1 = b10 + fx * (b11 - b10);
    float vb = (br0 + fy * (br1 - br0)) * s1;
    char* pxb = base + ((size_t)(h + 1) * 258 + (w + 1)) * 256;
    *(u32*)(pxb + 4 * cb) = pack2(va, vb);
    if (cb == 16){                           // zero ch 115..127 (bytes 230..255)
      *(u16*)(pxb + 230) = 0;
      #pragma unroll
      for (int k2 = 0; k2 < 6; k2++) *(u32*)(pxb + 232 + 4 * k2) = 0;
    }
  }
}

// ---------------- MFMA correlation: D[m][n] = sum_c ref[c][w0+m] * nb[c][ih][w0+n-4] ----------
// Per wave: 16 px, all 9 dy x 9 dx. A-frag loaded once (K=32 = all channels); per dy two B-frags
// (24-px shifted window) -> 2 MFMAs. Epilogue: predicated 2B stores, exactly-once per (px,ch).
__global__ __launch_bounds__(256) void k_corr_mfma(const u16* __restrict__ xrefT0,
    const u16* __restrict__ xnbT0, char* __restrict__ ws){
  const int tid = threadIdx.x;
  const int wv = tid >> 6, l = tid & 63;
  const int bx = blockIdx.x;
  const int bio = blockIdx.y;
  const u16* xrefT = xrefT0 + (size_t)bio * SE_XREF;
  const u16* xnbT  = xnbT0  + (size_t)bio * SE_XNB;
  const int r = bx & 255, sub = bx >> 8;
  const int h = (r & 7) * 32 + (r >> 3);     // XCD swizzle: nbT row reuse stays on-XCD
  const int w0 = (sub * 4 + wv) * 16;
  const int m16 = l & 15, g = l >> 4;

  uint4 ua = *(const uint4*)(xrefT + ((size_t)h * 256 + w0 + m16) * 32 + g * 8);
  bf16x8 av = __builtin_bit_cast(bf16x8, ua);

  size_t bOff = ((size_t)h * 272 + w0 + m16) * 32 + g * 8;
  char* outLane = ws + OFF_INPT + (size_t)bio * S_INPT
                  + ((size_t)(h + 1) * 258 + (w0 + 1)) * 256
                  + (size_t)(g * 4) * 256 + 68;
  const f32x4 z = {0.f, 0.f, 0.f, 0.f};
  #pragma unroll
  for (int dy = 0; dy < 9; dy++){
    uint4 ub0 = *(const uint4*)(xnbT + bOff);
    uint4 ub1 = *(const uint4*)(xnbT + bOff + 512);
    bOff += 8704;                            // next padded row (272*32)
    f32x4 d0 = __builtin_amdgcn_mfma_f32_16x16x32_bf16(av, __builtin_bit_cast(bf16x8, ub0), z, 0, 0, 0);
    f32x4 d1 = __builtin_amdgcn_mfma_f32_16x16x32_bf16(av, __builtin_bit_cast(bf16x8, ub1), z, 0, 0, 0);
    #pragma unroll
    for (int j = 0; j < 4; j++){
      int dxa = m16 - g * 4 - j;             // frag0: dx = n - m
      int dxb = dxa + 16;                    // frag1: dx = n + 16 - m
      bool va = (unsigned)dxa <= 8u;
      bool vb = (unsigned)dxb <= 8u;
      if (va | vb){
        float val = va ? d0[j] : d1[j];
        int dx = va ? dxa : dxb;
        float f = lrelu(val * 0.03125f);
        *(u16*)(outLane + j * 256 + (dy * 9 + dx) * 2) = f2bf(f);
      }
    }
  }
}

// ---------------- conv0: 128->32, MFMA implicit GEMM, weights LDS-chunked ---------------------
// R13: 2 output rows per block (halo fetch 3x -> 2x per row), 8 A-frags/wave for MLP.
// wave wv: row = rp*2 + (wv>>1), px-half = (wv&1)*128. grid (128, 4).
__global__ __launch_bounds__(256) void k_conv0(const u16* __restrict__ inT0, const u16* __restrict__ wt,
    const float* __restrict__ bias, u16* __restrict__ outA0){
  __shared__ __align__(16) u16 wl[32 * 648];
  const int tid = threadIdx.x;
  const int bx = blockIdx.x;
  const int bio = blockIdx.y;
  const u16* inT = inT0 + (size_t)bio * SE_INPT;
  u16* outA = outA0 + (size_t)bio * SE_H;
  const int rp = (bx & 7) * 16 + (bx >> 3);      // row-pair 0..127, XCD-banded
  const int wv = tid >> 6, ln = tid & 63, l15 = ln & 15, l4 = ln >> 4;
  const int row = rp * 2 + (wv >> 1);
  const int ph = (wv & 1) * 128;
  f32x4 acc[8][2] = {};
  const u16* aB[8];
  #pragma unroll
  for (int i = 0; i < 8; i++)
    aB[i] = inT + (size_t)(row * HP + (ph + i * 16 + l15)) * 128 + l4 * 8;

  // chunk 0: taps 0..3 (512 k-elems/row)
  for (int i = tid; i < 2048; i += 256){
    int co = i >> 6, q = i & 63;
    ((uint4*)&wl[co * 648])[q] = *(const uint4*)&wt[co * 1160 + q * 8];
  }
  __syncthreads();
  #pragma unroll
  for (int tap = 0; tap < 4; tap++){
    const int ky = tap / 3, kx = tap % 3;
    #pragma unroll
    for (int s = 0; s < 4; s++){
      bf16x8 bv[2];
      #pragma unroll
      for (int j = 0; j < 2; j++){
        uint4 u = *(const uint4*)&wl[(j * 16 + l15) * 648 + tap * 128 + s * 32 + l4 * 8];
        bv[j] = __builtin_bit_cast(bf16x8, u);
      }
      #pragma unroll
      for (int i = 0; i < 8; i++){
        uint4 ua = *(const uint4*)(aB[i] + (ky * HP + kx) * 128 + s * 32);
        bf16x8 av = __builtin_bit_cast(bf16x8, ua);
        #pragma unroll
        for (int j = 0; j < 2; j++)
          acc[i][j] = __builtin_amdgcn_mfma_f32_16x16x32_bf16(av, bv[j], acc[i][j], 0, 0, 0);
      }
    }
  }
  __syncthreads();
  // chunk 1: taps 4..8 (640 k-elems/row)
  for (int i = tid; i < 2560; i += 256){
    int co = i / 80, q = i % 80;
    ((uint4*)&wl[co * 648])[q] = *(const uint4*)&wt[co * 1160 + 512 + q * 8];
  }
  __syncthreads();
  #pragma unroll
  for (int tap = 4; tap < 9; tap++){
    const int ky = tap / 3, kx = tap % 3;
    #pragma unroll
    for (int s = 0; s < 4; s++){
      bf16x8 bv[2];
      #pragma unroll
      for (int j = 0; j < 2; j++){
        uint4 u = *(const uint4*)&wl[(j * 16 + l15) * 648 + (tap - 4) * 128 + s * 32 + l4 * 8];
        bv[j] = __builtin_bit_cast(bf16x8, u);
      }
      #pragma unroll
      for (int i = 0; i < 8; i++){
        uint4 ua = *(const uint4*)(aB[i] + (ky * HP + kx) * 128 + s * 32);
        bf16x8 av = __builtin_bit_cast(bf16x8, ua);
        #pragma unroll
        for (int j = 0; j < 2; j++)
          acc[i][j] = __builtin_amdgcn_mfma_f32_16x16x32_bf16(av, bv[j], acc[i][j], 0, 0, 0);
      }
    }
  }
  // epilogue: bias + lrelu -> hT halo layout (bf16)
  #pragma unroll
  for (int i = 0; i < 8; i++){
    const int pxb = ph + i * 16 + l4 * 4;
    #pragma unroll
    for (int j = 0; j < 2; j++){
      const int co = j * 16 + l15;
      const float bs = bias[co];
      #pragma unroll
      for (int r = 0; r < 4; r++){
        const int px = pxb + r;
        float v = lrelu(acc[i][j][r] + bs);
        outA[(size_t)((row + 1) * HP + px + 1) * 32 + co] = f2bf(v);
      }
    }
  }
}

// ---------------- 32-cin convs (conv1/conv2/convf), MFMA -------------------------------------
// R13: 2 output rows per block, 8 A-frags/wave. grid (128, 4).
// MODE 0: bias+lrelu -> halo outH (t1). MODE 1: +resid, lrelu -> halo outH (fea) AND fp32 out feats.
// MODE 2: flows (co 0,1) + sigmoid mask (co 2) -> fp32 out.
template<int NT, int MODE>
__global__ __launch_bounds__(256) void k_conv32(const u16* __restrict__ inT0, const u16* __restrict__ wt,
    const float* __restrict__ bias, u16* __restrict__ outH0, float* __restrict__ outF,
    const u16* __restrict__ resid0){
  constexpr int NR = (NT == 2) ? 32 : 16;
  __shared__ __align__(16) u16 wl[NR * 296];
  const int tid = threadIdx.x;
  const int bio = blockIdx.y;
  const u16* inT = inT0 + (size_t)bio * SE_H;
  for (int i = tid; i < NR * 296 / 8; i += 256)
    ((uint4*)wl)[i] = ((const uint4*)wt)[i];
  __syncthreads();
  const int bx = blockIdx.x;
  const int rp = (bx & 7) * 16 + (bx >> 3);      // row-pair 0..127
  const int wv = tid >> 6, ln = tid & 63, l15 = ln & 15, l4 = ln >> 4;
  const int row = rp * 2 + (wv >> 1);
  const int ph = (wv & 1) * 128;
  f32x4 acc[8][NT] = {};
  const u16* aB[8];
  #pragma unroll
  for (int i = 0; i < 8; i++)
    aB[i] = inT + (size_t)(row * HP + (ph + i * 16 + l15)) * 32 + l4 * 8;
  #pragma unroll
  for (int ky = 0; ky < 3; ky++){
    #pragma unroll
    for (int kx = 0; kx < 3; kx++){
      const int tap = ky * 3 + kx;
      bf16x8 bv[NT];
      #pragma unroll
      for (int j = 0; j < NT; j++){
        uint4 u = *(const uint4*)&wl[(j * 16 + l15) * 296 + tap * 32 + l4 * 8];
        bv[j] = __builtin_bit_cast(bf16x8, u);
      }
      #pragma unroll
      for (int i = 0; i < 8; i++){
        uint4 ua = *(const uint4*)(aB[i] + (ky * HP + kx) * 32);
        bf16x8 av = __builtin_bit_cast(bf16x8, ua);
        #pragma unroll
        for (int j = 0; j < NT; j++)
          acc[i][j] = __builtin_amdgcn_mfma_f32_16x16x32_bf16(av, bv[j], acc[i][j], 0, 0, 0);
      }
    }
  }
  #pragma unroll
  for (int i = 0; i < 8; i++){
    const int pxb = ph + i * 16 + l4 * 4;
    #pragma unroll
    for (int j = 0; j < NT; j++){
      const int co = j * 16 + l15;
      float bs;
      if constexpr (MODE == 2) bs = (co < 3) ? bias[co] : 0.f;
      else bs = bias[co];
      #pragma unroll
      for (int r = 0; r < 4; r++){
        const int px = pxb + r;
        float v = acc[i][j][r] + bs;
        if constexpr (MODE == 0){
          v = lrelu(v);
          outH0[(size_t)bio * SE_H + (size_t)((row + 1) * HP + px + 1) * 32 + co] = f2bf(v);
        } else if constexpr (MODE == 1){
          float hres = bf2f(resid0[(size_t)bio * SE_H + (size_t)((row + 1) * HP + px + 1) * 32 + co]);
          v = lrelu(v + hres);
          outH0[(size_t)bio * SE_H + (size_t)((row + 1) * HP + px + 1) * 32 + co] = f2bf(v); // feaT
          outF[786432 + ((size_t)(bio * 32 + co)) * 65536 + (size_t)row * 256 + px] = v;     // feats
        } else {
          if (co < 2)
            outF[((size_t)(bio * 2 + co)) * 65536 + (size_t)row * 256 + px] = v;             // flows
          else if (co == 2){
            float s = 1.f / (1.f + __expf(-v));
            outF[524288 + (size_t)bio * 65536 + (size_t)row * 256 + px] = s;                 // mask
          }
        }
      }
    }
  }
}

extern "C" void kernel_launch(void* const* d_in, const int* in_sizes, int n_in,
                              void* d_out, int out_size, void* d_ws, size_t ws_size,
                              hipStream_t stream){
  float* out = (float*)d_out;

  // ---- runtime interface verification (kept from R6; encodes any mismatch into out[0]) ----
  static const int exp_sizes[12] = {8388608, 8388608, 131072, 2097152,
                                    33120, 32, 9216, 32, 9216, 32, 864, 3};
  float sent = 0.f;
  if (n_in != 12) sent = 1.0e6f;
  else if (out_size != 9175040) sent = 2.0e6f;
  else {
    for (int i = 0; i < 12; i++)
      if (in_sizes[i] != exp_sizes[i]){ sent = 3.0e6f * (1.0f + 0.01f * i); break; }
    if (sent == 0.f && ws_size < WS_NEED)
      sent = 16.0f * (float)(ws_size >> 20);
  }
  if (sent != 0.f){
    hipLaunchKernelGGL(k_sent, dim3(1), dim3(64), 0, stream, out, sent);
    return;
  }

  const float* xref  = (const float*)d_in[0];
  const float* xnb   = (const float*)d_in[1];
  const float* bflow = (const float*)d_in[2];
  const float* bfeat = (const float*)d_in[3];
  const float* w0 = (const float*)d_in[4];
  const float* b0 = (const float*)d_in[5];
  const float* w1 = (const float*)d_in[6];
  const float* b1 = (const float*)d_in[7];
  const float* w2 = (const float*)d_in[8];
  const float* b2 = (const float*)d_in[9];
  const float* wf = (const float*)d_in[10];
  const float* bf = (const float*)d_in[11];
  char* ws = (char*)d_ws;
  u16* wse   = (u16*)d_ws;
  u16* inpT  = (u16*)(ws + OFF_INPT);
  u16* hT    = (u16*)(ws + OFF_HT);
  u16* t1T   = (u16*)(ws + OFF_T1);
  u16* feaT  = (u16*)(ws + OFF_FEA);
  u16* xrefT = (u16*)(ws + OFF_XREFT);
  u16* xnbT  = (u16*)(ws + OFF_XNBT);

  hipLaunchKernelGGL(k_halo, dim3(261, 4), dim3(256), 0, stream, ws);
  hipLaunchKernelGGL(k_wprep, dim3(64), dim3(256), 0, stream, w0, w1, w2, wf, wse);
  hipLaunchKernelGGL(k_xpose, dim3(520, 4), dim3(320), 0, stream, xref, xnb, xrefT, xnbT);
  hipLaunchKernelGGL(k_up, dim3(4352, 4), dim3(64), 0, stream, bflow, bfeat, ws);
  hipLaunchKernelGGL(k_corr_mfma, dim3(1024, 4), dim3(256), 0, stream, xrefT, xnbT, ws);
  hipLaunchKernelGGL(k_conv0, dim3(128, 4), dim3(256), 0, stream, inpT, wse + E_WT0, b0, hT);
  hipLaunchKernelGGL((k_conv32<2, 0>), dim3(128, 4), dim3(256), 0, stream,
                     hT, wse + E_WT1, b1, t1T, (float*)nullptr, (const u16*)nullptr);
  hipLaunchKernelGGL((k_conv32<2, 1>), dim3(128, 4), dim3(256), 0, stream,
                     t1T, wse + E_WT2, b2, feaT, out, hT);
  hipLaunchKernelGGL((k_conv32<1, 2>), dim3(128, 4), dim3(256), 0, stream,
                     feaT, wse + E_WTF, bf, (u16*)nullptr, out, (const u16*)nullptr);
}

// Round 6
// 314.183 us; speedup vs baseline: 2.3212x; 1.2944x over previous
//
#include <hip/hip_runtime.h>

typedef unsigned short u16;
typedef unsigned int u32;
typedef __bf16 bf16x8 __attribute__((ext_vector_type(8)));
typedef float f32x4 __attribute__((ext_vector_type(4)));

#define HP 258
// weight-table element offsets within ws (u16 units)
#define E_WT0 0
#define E_WT1 37120
#define E_WT2 46592
#define E_WTF 56064
// ---- per-batch strided layout: all 4 batches resident simultaneously ----
// 258*258 = 66564 pixels. R14: inpT is CHUNK-MAJOR [4 ch-chunks][66564 px][32 ch] bf16.
#define C_CH      4260096ull             // one chunk = 66564*32*2 B
#define OFF_INPT  131072ull
#define S_INPT    17040384ull            // 4*C_CH
#define OFF_HT    68292608ull            // OFF_INPT + 4*S_INPT
#define S_H       4260096ull             // 66564*32*2
#define OFF_T1    85332992ull            // OFF_HT + 4*S_H
#define OFF_FEA   102373376ull           // OFF_T1 + 4*S_H
#define OFF_XREFT 119413760ull           // OFF_FEA + 4*S_H
#define S_XREF    4194304ull             // 256*256*32*2
#define OFF_XNBT  136190976ull           // OFF_XREFT + 4*S_XREF
#define S_XNB     4595712ull             // 264*272*32*2
#define WS_NEED   154573824ull           // OFF_XNBT + 4*S_XNB  (ws is 256 MiB per R2 fill evidence)
// u16-element strides
#define SE_INPT 8520192u
#define SE_H    2130048u
#define SE_XREF 2097152u
#define SE_XNB  2297856u

__device__ __forceinline__ float bf2f(u16 u){ u32 x = ((u32)u) << 16; return __builtin_bit_cast(float, x); }
__device__ __forceinline__ u16 f2bf(float f){
  u32 x = __builtin_bit_cast(u32, f);
  return (u16)((x + 0x7fffu + ((x >> 16) & 1u)) >> 16);   // RNE
}
__device__ __forceinline__ u32 pack2(float a, float b){ return (u32)f2bf(a) | ((u32)f2bf(b) << 16); }
__device__ __forceinline__ float lrelu(float x){ return x >= 0.f ? x : 0.1f * x; }

__global__ void k_sent(float* __restrict__ out, float val){
  if (threadIdx.x == 0 && blockIdx.x == 0) out[0] = val;
}

// ---------------- halo-ring zeroing for all four per-batch buffer sets (once per launch) ------
__global__ __launch_bounds__(256) void k_halo(char* __restrict__ ws){
  int idx = blockIdx.x * 256 + threadIdx.x;
  const int bio = blockIdx.y;
  if (idx >= 258 * 258) return;
  int y = idx / 258;
  int x = idx - y * 258;
  if (y != 0 && y != 257 && x != 0 && x != 257) return;
  uint4 z = make_uint4(0u, 0u, 0u, 0u);
  size_t pix = (size_t)idx;
  #pragma unroll
  for (int s = 0; s < 4; s++){
    uint4* p0 = (uint4*)(ws + OFF_INPT + (size_t)bio * S_INPT + (size_t)s * C_CH + pix * 64);
    #pragma unroll
    for (int k = 0; k < 4; k++) p0[k] = z;
  }
  uint4* p1 = (uint4*)(ws + OFF_HT  + (size_t)bio * S_H + pix * 64);
  uint4* p2 = (uint4*)(ws + OFF_T1  + (size_t)bio * S_H + pix * 64);
  uint4* p3 = (uint4*)(ws + OFF_FEA + (size_t)bio * S_H + pix * 64);
  #pragma unroll
  for (int k = 0; k < 4; k++){ p1[k] = z; p2[k] = z; p3[k] = z; }
}

// ---------------- weight re-layout: Wt[co][tap*Cpad + c], tap-major K, channel-permuted -------
// inpT channel order: 0..31 up-feat, 32..33 flow, 34..114 corr(dy*9+dx), 115..127 zero.
// Original (R8-verified) w0 input-channel order: 0..80 corr, 81..112 feat, 113..114 flow.
__global__ __launch_bounds__(256) void k_wprep(const float* __restrict__ w0, const float* __restrict__ w1,
    const float* __restrict__ w2, const float* __restrict__ wf, u16* __restrict__ wse){
  for (int idx = blockIdx.x * 256 + threadIdx.x; idx < 60800; idx += 64 * 256){
    float v = 0.f;
    if (idx < 37120){                       // Wt0: 32 rows x 1160 (K=9*128=1152 used)
      int co = idx / 1160, kk = idx % 1160;
      if (kk < 1152){
        int tap = kk >> 7, c = kk & 127;
        if (c < 115){
          int oc = (c < 34) ? (81 + c) : (c - 34);
          v = w0[(co * 115 + oc) * 9 + tap];
        }
      }
    } else if (idx < 46592){                // Wt1: 32 x 296 (K=9*32=288)
      int r = idx - 37120; int co = r / 296, kk = r % 296;
      if (kk < 288){ int tap = kk >> 5, c = kk & 31; v = w1[(co * 32 + c) * 9 + tap]; }
    } else if (idx < 56064){                // Wt2
      int r = idx - 46592; int co = r / 296, kk = r % 296;
      if (kk < 288){ int tap = kk >> 5, c = kk & 31; v = w2[(co * 32 + c) * 9 + tap]; }
    } else {                                // Wtf: 16 x 296, rows 3..15 zero
      int r = idx - 56064; int co = r / 296, kk = r % 296;
      if (kk < 288 && co < 3){ int tap = kk >> 5, c = kk & 31; v = wf[(co * 32 + c) * 9 + tap]; }
    }
    wse[idx] = f2bf(v);
  }
}

// ---------------- transpose prepass: [c][h][w] fp32 -> [h][w][c] bf16 -------------------------
// blocks 0..255: xrefT row h (no pad). blocks 256..519: xnbT padded row hp (rows -4..259, px -4..267).
__global__ __launch_bounds__(320) void k_xpose(const float* __restrict__ xref,
    const float* __restrict__ xnb, u16* __restrict__ xrefT0, u16* __restrict__ xnbT0){
  const int t = threadIdx.x;
  const int bxx = blockIdx.x;
  const int bio = blockIdx.y;
  u16* xrefT = xrefT0 + (size_t)bio * SE_XREF;
  u16* xnbT  = xnbT0  + (size_t)bio * SE_XNB;
  float v[32];
  u32 p[16];
  if (bxx < 256){
    if (t >= 256) return;
    const float* src = xref + ((size_t)bio * 32) * 65536 + (size_t)bxx * 256 + t;
    #pragma unroll
    for (int c = 0; c < 32; c++) v[c] = src[(size_t)c * 65536];
    #pragma unroll
    for (int k = 0; k < 16; k++) p[k] = pack2(v[2 * k], v[2 * k + 1]);
    uint4* dst = (uint4*)(xrefT + ((size_t)bxx * 256 + t) * 32);
    #pragma unroll
    for (int q = 0; q < 4; q++) dst[q] = ((uint4*)p)[q];
  } else {
    if (t >= 272) return;
    const int hp = bxx - 256;
    const int ih = hp - 4, px = t - 4;
    uint4* dst = (uint4*)(xnbT + ((size_t)hp * 272 + t) * 32);
    if (ih >= 0 && ih <= 255 && px >= 0 && px <= 255){
      const float* src = xnb + ((size_t)bio * 32) * 65536 + (size_t)ih * 256 + px;
      #pragma unroll
      for (int c = 0; c < 32; c++) v[c] = src[(size_t)c * 65536];
      #pragma unroll
      for (int k = 0; k < 16; k++) p[k] = pack2(v[2 * k], v[2 * k + 1]);
      #pragma unroll
      for (int q = 0; q < 4; q++) dst[q] = ((uint4*)p)[q];
    } else {
      uint4 zz = make_uint4(0u, 0u, 0u, 0u);
      #pragma unroll
      for (int q = 0; q < 4; q++) dst[q] = zz;
    }
  }
}

// ---------------- bilinear 2x upsample (ch 0..33) + zero tail ch 115..127 ---------------------
// grid = (17 channel-pairs x 256 rows, 4 batches), 64 threads, 4 px/thread. chunk-major inpT.
__global__ __launch_bounds__(64) void k_up(const float* __restrict__ bflow,
    const float* __restrict__ bfeat, char* __restrict__ ws){
  const int t = threadIdx.x;
  const int bx = blockIdx.x;
  const int bio = blockIdx.y;
  const int cb = bx >> 8;                    // 0..16
  const int r = bx & 255;
  const int h = (r & 7) * 32 + (r >> 3);     // XCD swizzle
  const int c0 = 2 * cb;
  const float* pl0 = (c0 < 32) ? (bfeat + ((size_t)(bio * 32 + c0)) * 16384)
                               : (bflow + ((size_t)(bio * 2 + (c0 - 32))) * 16384);
  const float* pl1 = (c0 < 31) ? (bfeat + ((size_t)(bio * 32 + c0 + 1)) * 16384)
                               : (bflow + ((size_t)(bio * 2 + (c0 - 31))) * 16384);
  const float s0 = (c0 >= 32) ? 2.f : 1.f;
  const float s1 = (c0 + 1 >= 32) ? 2.f : 1.f;
  int y0 = (h >> 1) - 1 + (h & 1);
  float fy = (h & 1) ? 0.25f : 0.75f;
  int y0o = (y0 < 0 ? 0 : y0) * 128;
  int y1o = ((y0 + 1) > 127 ? 127 : (y0 + 1)) * 128;
  char* base = ws + OFF_INPT + (size_t)bio * S_INPT;
  #pragma unroll
  for (int pp = 0; pp < 4; pp++){
    int w = 4 * t + pp;
    int x0 = (w >> 1) - 1 + (w & 1);
    float fx = (w & 1) ? 0.25f : 0.75f;
    int x0c = x0 < 0 ? 0 : x0;
    int x1c = (x0 + 1) > 127 ? 127 : (x0 + 1);
    float a00 = pl0[y0o + x0c], a01 = pl0[y0o + x1c];
    float a10 = pl0[y1o + x0c], a11 = pl0[y1o + x1c];
    float ar0 = a00 + fx * (a01 - a00), ar1 = a10 + fx * (a11 - a10);
    float va = (ar0 + fy * (ar1 - ar0)) * s0;
    float b00 = pl1[y0o + x0c], b01 = pl1[y0o + x1c];
    float b10 = pl1[y1o + x0c], b11 = pl1[y1o + x1c];
    float br0 = b00 + fx * (b01 - b00), br1 = b10 + fx * (b11 - b10);
    float vb = (br0 + fy * (br1 - br0)) * s1;
    char* pxb = base + ((size_t)(h + 1) * 258 + (w + 1)) * 64;
    if (cb < 16){
      *(u32*)(pxb + 4 * cb) = pack2(va, vb);            // chunk 0, ch 2cb..2cb+1
    } else {
      *(u32*)(pxb + C_CH) = pack2(va, vb);              // chunk 1, ch 0..1 (flow)
      *(u16*)(pxb + 3 * C_CH + 38) = 0;                 // chunk 3 ch 19..31 zero tail
      #pragma unroll
      for (int k2 = 0; k2 < 6; k2++) *(u32*)(pxb + 3 * C_CH + 40 + 4 * k2) = 0;
    }
  }
}

// ---------------- MFMA correlation: D[m][n] = sum_c ref[c][w0+m] * nb[c][ih][w0+n-4] ----------
// Per wave: 16 px, all 9 dy x 9 dx. Epilogue: predicated 2B stores into chunk-major inpT.
__global__ __launch_bounds__(256) void k_corr_mfma(const u16* __restrict__ xrefT0,
    const u16* __restrict__ xnbT0, char* __restrict__ ws){
  const int tid = threadIdx.x;
  const int wv = tid >> 6, l = tid & 63;
  const int bx = blockIdx.x;
  const int bio = blockIdx.y;
  const u16* xrefT = xrefT0 + (size_t)bio * SE_XREF;
  const u16* xnbT  = xnbT0  + (size_t)bio * SE_XNB;
  const int r = bx & 255, sub = bx >> 8;
  const int h = (r & 7) * 32 + (r >> 3);     // XCD swizzle: nbT row reuse stays on-XCD
  const int w0 = (sub * 4 + wv) * 16;
  const int m16 = l & 15, g = l >> 4;

  uint4 ua = *(const uint4*)(xrefT + ((size_t)h * 256 + w0 + m16) * 32 + g * 8);
  bf16x8 av = __builtin_bit_cast(bf16x8, ua);

  size_t bOff = ((size_t)h * 272 + w0 + m16) * 32 + g * 8;
  char* ob = ws + OFF_INPT + (size_t)bio * S_INPT
             + ((size_t)(h + 1) * 258 + (w0 + 1) + g * 4) * 64;
  const f32x4 z = {0.f, 0.f, 0.f, 0.f};
  #pragma unroll
  for (int dy = 0; dy < 9; dy++){
    uint4 ub0 = *(const uint4*)(xnbT + bOff);
    uint4 ub1 = *(const uint4*)(xnbT + bOff + 512);
    bOff += 8704;                            // next padded row (272*32)
    f32x4 d0 = __builtin_amdgcn_mfma_f32_16x16x32_bf16(av, __builtin_bit_cast(bf16x8, ub0), z, 0, 0, 0);
    f32x4 d1 = __builtin_amdgcn_mfma_f32_16x16x32_bf16(av, __builtin_bit_cast(bf16x8, ub1), z, 0, 0, 0);
    #pragma unroll
    for (int j = 0; j < 4; j++){
      int dxa = m16 - g * 4 - j;             // frag0: dx = n - m
      int dxb = dxa + 16;                    // frag1: dx = n + 16 - m
      bool va = (unsigned)dxa <= 8u;
      bool vb = (unsigned)dxb <= 8u;
      if (va | vb){
        float val = va ? d0[j] : d1[j];
        int dx = va ? dxa : dxb;
        float f = lrelu(val * 0.03125f);
        int c = 34 + dy * 9 + dx;            // chunk-major channel
        *(u16*)(ob + j * 64 + (size_t)(c >> 5) * C_CH + (c & 31) * 2) = f2bf(f);
      }
    }
  }
}

// ---------------- conv0: 128->32, LDS-staged input (s-chunked), weights from global(L2) ------
// R14: block = 4 out rows x 128 px, 4 waves (wave = 1 row). Per s-chunk: stage [6 rows][130 px][32ch]
// (49.9 KB LDS, 3 blocks/CU), each input byte read from HBM exactly once per block.
__global__ __launch_bounds__(256) void k_conv0(const u16* __restrict__ inT0, const u16* __restrict__ wt,
    const float* __restrict__ bias, u16* __restrict__ outA0){
  __shared__ __align__(16) u16 inL[24960];       // [6][130][32]
  const int tid = threadIdx.x;
  const int bx = blockIdx.x;
  const int bio = blockIdx.y;
  const u16* inT = inT0 + (size_t)bio * SE_INPT;
  u16* outA = outA0 + (size_t)bio * SE_H;
  const int rq = (bx & 7) * 8 + ((bx >> 3) & 7); // row-quad 0..63, XCD-banded
  const int ph = bx >> 6;                        // px half
  const int row0 = rq * 4, p0 = ph * 128;
  const int wv = tid >> 6, ln = tid & 63, l15 = ln & 15, l4 = ln >> 4;
  f32x4 acc[8][2] = {};

  for (int s = 0; s < 4; s++){
    // stage input chunk s: halo rows row0..row0+5, halo px p0..p0+129 (each byte once)
    for (int i = tid; i < 3120; i += 256){
      int rr = i / 520, q = i - rr * 520;
      int pxi = q >> 2, cq = q & 3;
      const u16* src = inT + ((size_t)s * 66564 + (size_t)(row0 + rr) * 258 + (p0 + pxi)) * 32 + cq * 8;
      ((uint4*)inL)[(rr * 130 + pxi) * 4 + cq] = *(const uint4*)src;
    }
    __syncthreads();
    #pragma unroll
    for (int ky = 0; ky < 3; ky++){
      #pragma unroll
      for (int kx = 0; kx < 3; kx++){
        const int tap = ky * 3 + kx;
        bf16x8 bv[2];
        #pragma unroll
        for (int j = 0; j < 2; j++){
          uint4 u = *(const uint4*)(wt + (size_t)(j * 16 + l15) * 1160 + tap * 128 + s * 32 + l4 * 8);
          bv[j] = __builtin_bit_cast(bf16x8, u);
        }
        #pragma unroll
        for (int t = 0; t < 8; t++){
          uint4 uai = *(const uint4*)&inL[((wv + ky) * 130 + t * 16 + l15 + kx) * 32 + l4 * 8];
          bf16x8 av = __builtin_bit_cast(bf16x8, uai);
          #pragma unroll
          for (int j = 0; j < 2; j++)
            acc[t][j] = __builtin_amdgcn_mfma_f32_16x16x32_bf16(av, bv[j], acc[t][j], 0, 0, 0);
        }
      }
    }
    __syncthreads();
  }
  // epilogue: wave wv owns out row row0+wv; bias + lrelu -> hT halo layout
  const int row = row0 + wv;
  #pragma unroll
  for (int t = 0; t < 8; t++){
    const int pxb = p0 + t * 16 + l4 * 4;
    #pragma unroll
    for (int j = 0; j < 2; j++){
      const int co = j * 16 + l15;
      const float bs = bias[co];
      #pragma unroll
      for (int r = 0; r < 4; r++){
        const int px = pxb + r;
        float v = lrelu(acc[t][j][r] + bs);
        outA[(size_t)((row + 1) * HP + px + 1) * 32 + co] = f2bf(v);
      }
    }
  }
}

// ---------------- 32-cin convs (conv1/conv2/convf), LDS-staged input, global weights ---------
// R14: block = 4 out rows x 128 px, 4 waves. Stage [6][130][32] once (49.9 KB), weights from L2.
// MODE 0: bias+lrelu -> halo outH (t1). MODE 1: +resid, lrelu -> halo outH (fea) AND fp32 out feats.
// MODE 2: flows (co 0,1) + sigmoid mask (co 2) -> fp32 out.
template<int NT, int MODE>
__global__ __launch_bounds__(256) void k_conv32(const u16* __restrict__ inT0, const u16* __restrict__ wt,
    const float* __restrict__ bias, u16* __restrict__ outH0, float* __restrict__ outF,
    const u16* __restrict__ resid0){
  __shared__ __align__(16) u16 inL[24960];       // [6][130][32]
  const int tid = threadIdx.x;
  const int bx = blockIdx.x;
  const int bio = blockIdx.y;
  const u16* inT = inT0 + (size_t)bio * SE_H;
  const int rq = (bx & 7) * 8 + ((bx >> 3) & 7);
  const int ph = bx >> 6;
  const int row0 = rq * 4, p0 = ph * 128;
  const int wv = tid >> 6, ln = tid & 63, l15 = ln & 15, l4 = ln >> 4;

  for (int i = tid; i < 3120; i += 256){
    int rr = i / 520, q = i - rr * 520;
    int pxi = q >> 2, cq = q & 3;
    const u16* src = inT + ((size_t)(row0 + rr) * 258 + (p0 + pxi)) * 32 + cq * 8;
    ((uint4*)inL)[(rr * 130 + pxi) * 4 + cq] = *(const uint4*)src;
  }
  __syncthreads();

  f32x4 acc[8][NT] = {};
  #pragma unroll
  for (int ky = 0; ky < 3; ky++){
    #pragma unroll
    for (int kx = 0; kx < 3; kx++){
      const int tap = ky * 3 + kx;
      bf16x8 bv[NT];
      #pragma unroll
      for (int j = 0; j < NT; j++){
        uint4 u = *(const uint4*)(wt + (size_t)(j * 16 + l15) * 296 + tap * 32 + l4 * 8);
        bv[j] = __builtin_bit_cast(bf16x8, u);
      }
      #pragma unroll
      for (int t = 0; t < 8; t++){
        uint4 uai = *(const uint4*)&inL[((wv + ky) * 130 + t * 16 + l15 + kx) * 32 + l4 * 8];
        bf16x8 av = __builtin_bit_cast(bf16x8, uai);
        #pragma unroll
        for (int j = 0; j < NT; j++)
          acc[t][j] = __builtin_amdgcn_mfma_f32_16x16x32_bf16(av, bv[j], acc[t][j], 0, 0, 0);
      }
    }
  }
  const int row = row0 + wv;
  #pragma unroll
  for (int t = 0; t < 8; t++){
    const int pxb = p0 + t * 16 + l4 * 4;
    #pragma unroll
    for (int j = 0; j < NT; j++){
      const int co = j * 16 + l15;
      float bs;
      if constexpr (MODE == 2) bs = (co < 3) ? bias[co] : 0.f;
      else bs = bias[co];
      #pragma unroll
      for (int r = 0; r < 4; r++){
        const int px = pxb + r;
        float v = acc[t][j][r] + bs;
        if constexpr (MODE == 0){
          v = lrelu(v);
          outH0[(size_t)bio * SE_H + (size_t)((row + 1) * HP + px + 1) * 32 + co] = f2bf(v);
        } else if constexpr (MODE == 1){
          float hres = bf2f(resid0[(size_t)bio * SE_H + (size_t)((row + 1) * HP + px + 1) * 32 + co]);
          v = lrelu(v + hres);
          outH0[(size_t)bio * SE_H + (size_t)((row + 1) * HP + px + 1) * 32 + co] = f2bf(v); // feaT
          outF[786432 + ((size_t)(bio * 32 + co)) * 65536 + (size_t)row * 256 + px] = v;     // feats
        } else {
          if (co < 2)
            outF[((size_t)(bio * 2 + co)) * 65536 + (size_t)row * 256 + px] = v;             // flows
          else if (co == 2){
            float s = 1.f / (1.f + __expf(-v));
            outF[524288 + (size_t)bio * 65536 + (size_t)row * 256 + px] = s;                 // mask
          }
        }
      }
    }
  }
}

extern "C" void kernel_launch(void* const* d_in, const int* in_sizes, int n_in,
                              void* d_out, int out_size, void* d_ws, size_t ws_size,
                              hipStream_t stream){
  float* out = (float*)d_out;

  // ---- runtime interface verification (kept from R6; encodes any mismatch into out[0]) ----
  static const int exp_sizes[12] = {8388608, 8388608, 131072, 2097152,
                                    33120, 32, 9216, 32, 9216, 32, 864, 3};
  float sent = 0.f;
  if (n_in != 12) sent = 1.0e6f;
  else if (out_size != 9175040) sent = 2.0e6f;
  else {
    for (int i = 0; i < 12; i++)
      if (in_sizes[i] != exp_sizes[i]){ sent = 3.0e6f * (1.0f + 0.01f * i); break; }
    if (sent == 0.f && ws_size < WS_NEED)
      sent = 16.0f * (float)(ws_size >> 20);
  }
  if (sent != 0.f){
    hipLaunchKernelGGL(k_sent, dim3(1), dim3(64), 0, stream, out, sent);
    return;
  }

  const float* xref  = (const float*)d_in[0];
  const float* xnb   = (const float*)d_in[1];
  const float* bflow = (const float*)d_in[2];
  const float* bfeat = (const float*)d_in[3];
  const float* w0 = (const float*)d_in[4];
  const float* b0 = (const float*)d_in[5];
  const float* w1 = (const float*)d_in[6];
  const float* b1 = (const float*)d_in[7];
  const float* w2 = (const float*)d_in[8];
  const float* b2 = (const float*)d_in[9];
  const float* wf = (const float*)d_in[10];
  const float* bf = (const float*)d_in[11];
  char* ws = (char*)d_ws;
  u16* wse   = (u16*)d_ws;
  u16* inpT  = (u16*)(ws + OFF_INPT);
  u16* hT    = (u16*)(ws + OFF_HT);
  u16* t1T   = (u16*)(ws + OFF_T1);
  u16* feaT  = (u16*)(ws + OFF_FEA);
  u16* xrefT = (u16*)(ws + OFF_XREFT);
  u16* xnbT  = (u16*)(ws + OFF_XNBT);

  hipLaunchKernelGGL(k_halo, dim3(261, 4), dim3(256), 0, stream, ws);
  hipLaunchKernelGGL(k_wprep, dim3(64), dim3(256), 0, stream, w0, w1, w2, wf, wse);
  hipLaunchKernelGGL(k_xpose, dim3(520, 4), dim3(320), 0, stream, xref, xnb, xrefT, xnbT);
  hipLaunchKernelGGL(k_up, dim3(4352, 4), dim3(64), 0, stream, bflow, bfeat, ws);
  hipLaunchKernelGGL(k_corr_mfma, dim3(1024, 4), dim3(256), 0, stream, xrefT, xnbT, ws);
  hipLaunchKernelGGL(k_conv0, dim3(128, 4), dim3(256), 0, stream, inpT, wse + E_WT0, b0, hT);
  hipLaunchKernelGGL((k_conv32<2, 0>), dim3(128, 4), dim3(256), 0, stream,
                     hT, wse + E_WT1, b1, t1T, (float*)nullptr, (const u16*)nullptr);
  hipLaunchKernelGGL((k_conv32<2, 1>), dim3(128, 4), dim3(256), 0, stream,
                     t1T, wse + E_WT2, b2, feaT, out, hT);
  hipLaunchKernelGGL((k_conv32<1, 2>), dim3(128, 4), dim3(256), 0, stream,
                     feaT, wse + E_WTF, bf, (u16*)nullptr, out, (const u16*)nullptr);
}

// Round 7
// 294.912 us; speedup vs baseline: 2.4729x; 1.0653x over previous
//
#include <hip/hip_runtime.h>

typedef unsigned short u16;
typedef unsigned int u32;
typedef __bf16 bf16x8 __attribute__((ext_vector_type(8)));
typedef float f32x4 __attribute__((ext_vector_type(4)));

#define HP 258
// weight-table element offsets within ws (u16 units)
#define E_WT0 0
#define E_WT1 37120
#define E_WT2 46592
#define E_WTF 56064
// ---- per-batch strided layout: all 4 batches resident simultaneously ----
// 258*258 = 66564 pixels. R14: inpT is CHUNK-MAJOR [4 ch-chunks][66564 px][32 ch] bf16.
#define C_CH      4260096ull             // one chunk = 66564*32*2 B
#define OFF_INPT  131072ull
#define S_INPT    17040384ull            // 4*C_CH
#define OFF_HT    68292608ull            // OFF_INPT + 4*S_INPT
#define S_H       4260096ull             // 66564*32*2
#define OFF_T1    85332992ull            // OFF_HT + 4*S_H
#define OFF_FEA   102373376ull           // OFF_T1 + 4*S_H
#define OFF_XREFT 119413760ull           // OFF_FEA + 4*S_H
#define S_XREF    4194304ull             // 256*256*32*2
#define OFF_XNBT  136190976ull           // OFF_XREFT + 4*S_XREF
#define S_XNB     4595712ull             // 264*272*32*2
#define WS_NEED   154573824ull           // OFF_XNBT + 4*S_XNB  (ws is 256 MiB per R2 fill evidence)
// u16-element strides
#define SE_INPT 8520192u
#define SE_H    2130048u
#define SE_XREF 2097152u
#define SE_XNB  2297856u

__device__ __forceinline__ float bf2f(u16 u){ u32 x = ((u32)u) << 16; return __builtin_bit_cast(float, x); }
__device__ __forceinline__ u16 f2bf(float f){
  u32 x = __builtin_bit_cast(u32, f);
  return (u16)((x + 0x7fffu + ((x >> 16) & 1u)) >> 16);   // RNE
}
__device__ __forceinline__ u32 pack2(float a, float b){ return (u32)f2bf(a) | ((u32)f2bf(b) << 16); }
__device__ __forceinline__ float lrelu(float x){ return x >= 0.f ? x : 0.1f * x; }

__global__ void k_sent(float* __restrict__ out, float val){
  if (threadIdx.x == 0 && blockIdx.x == 0) out[0] = val;
}

// ---------------- halo-ring zeroing for all four per-batch buffer sets (once per launch) ------
__global__ __launch_bounds__(256) void k_halo(char* __restrict__ ws){
  int idx = blockIdx.x * 256 + threadIdx.x;
  const int bio = blockIdx.y;
  if (idx >= 258 * 258) return;
  int y = idx / 258;
  int x = idx - y * 258;
  if (y != 0 && y != 257 && x != 0 && x != 257) return;
  uint4 z = make_uint4(0u, 0u, 0u, 0u);
  size_t pix = (size_t)idx;
  #pragma unroll
  for (int s = 0; s < 4; s++){
    uint4* p0 = (uint4*)(ws + OFF_INPT + (size_t)bio * S_INPT + (size_t)s * C_CH + pix * 64);
    #pragma unroll
    for (int k = 0; k < 4; k++) p0[k] = z;
  }
  uint4* p1 = (uint4*)(ws + OFF_HT  + (size_t)bio * S_H + pix * 64);
  uint4* p2 = (uint4*)(ws + OFF_T1  + (size_t)bio * S_H + pix * 64);
  uint4* p3 = (uint4*)(ws + OFF_FEA + (size_t)bio * S_H + pix * 64);
  #pragma unroll
  for (int k = 0; k < 4; k++){ p1[k] = z; p2[k] = z; p3[k] = z; }
}

// ---------------- weight re-layout: Wt[co][tap*Cpad + c], tap-major K, channel-permuted -------
// inpT channel order: 0..31 up-feat, 32..33 flow, 34..114 corr(dy*9+dx), 115..127 zero.
// Original (R8-verified) w0 input-channel order: 0..80 corr, 81..112 feat, 113..114 flow.
__global__ __launch_bounds__(256) void k_wprep(const float* __restrict__ w0, const float* __restrict__ w1,
    const float* __restrict__ w2, const float* __restrict__ wf, u16* __restrict__ wse){
  for (int idx = blockIdx.x * 256 + threadIdx.x; idx < 60800; idx += 64 * 256){
    float v = 0.f;
    if (idx < 37120){                       // Wt0: 32 rows x 1160 (K=9*128=1152 used)
      int co = idx / 1160, kk = idx % 1160;
      if (kk < 1152){
        int tap = kk >> 7, c = kk & 127;
        if (c < 115){
          int oc = (c < 34) ? (81 + c) : (c - 34);
          v = w0[(co * 115 + oc) * 9 + tap];
        }
      }
    } else if (idx < 46592){                // Wt1: 32 x 296 (K=9*32=288)
      int r = idx - 37120; int co = r / 296, kk = r % 296;
      if (kk < 288){ int tap = kk >> 5, c = kk & 31; v = w1[(co * 32 + c) * 9 + tap]; }
    } else if (idx < 56064){                // Wt2
      int r = idx - 46592; int co = r / 296, kk = r % 296;
      if (kk < 288){ int tap = kk >> 5, c = kk & 31; v = w2[(co * 32 + c) * 9 + tap]; }
    } else {                                // Wtf: 16 x 296, rows 3..15 zero
      int r = idx - 56064; int co = r / 296, kk = r % 296;
      if (kk < 288 && co < 3){ int tap = kk >> 5, c = kk & 31; v = wf[(co * 32 + c) * 9 + tap]; }
    }
    wse[idx] = f2bf(v);
  }
}

// ---------------- transpose prepass: [c][h][w] fp32 -> [h][w][c] bf16 -------------------------
// blocks 0..255: xrefT row h (no pad). blocks 256..519: xnbT padded row hp (rows -4..259, px -4..267).
__global__ __launch_bounds__(320) void k_xpose(const float* __restrict__ xref,
    const float* __restrict__ xnb, u16* __restrict__ xrefT0, u16* __restrict__ xnbT0){
  const int t = threadIdx.x;
  const int bxx = blockIdx.x;
  const int bio = blockIdx.y;
  u16* xrefT = xrefT0 + (size_t)bio * SE_XREF;
  u16* xnbT  = xnbT0  + (size_t)bio * SE_XNB;
  float v[32];
  u32 p[16];
  if (bxx < 256){
    if (t >= 256) return;
    const float* src = xref + ((size_t)bio * 32) * 65536 + (size_t)bxx * 256 + t;
    #pragma unroll
    for (int c = 0; c < 32; c++) v[c] = src[(size_t)c * 65536];
    #pragma unroll
    for (int k = 0; k < 16; k++) p[k] = pack2(v[2 * k], v[2 * k + 1]);
    uint4* dst = (uint4*)(xrefT + ((size_t)bxx * 256 + t) * 32);
    #pragma unroll
    for (int q = 0; q < 4; q++) dst[q] = ((uint4*)p)[q];
  } else {
    if (t >= 272) return;
    const int hp = bxx - 256;
    const int ih = hp - 4, px = t - 4;
    uint4* dst = (uint4*)(xnbT + ((size_t)hp * 272 + t) * 32);
    if (ih >= 0 && ih <= 255 && px >= 0 && px <= 255){
      const float* src = xnb + ((size_t)bio * 32) * 65536 + (size_t)ih * 256 + px;
      #pragma unroll
      for (int c = 0; c < 32; c++) v[c] = src[(size_t)c * 65536];
      #pragma unroll
      for (int k = 0; k < 16; k++) p[k] = pack2(v[2 * k], v[2 * k + 1]);
      #pragma unroll
      for (int q = 0; q < 4; q++) dst[q] = ((uint4*)p)[q];
    } else {
      uint4 zz = make_uint4(0u, 0u, 0u, 0u);
      #pragma unroll
      for (int q = 0; q < 4; q++) dst[q] = zz;
    }
  }
}

// ---------------- bilinear 2x upsample: thread = 1 px, ALL 34 channels -----------------------
// R15: chunk-0 (ch0..31) written as one contiguous 64 B line per thread (wave = 4 KB / instr);
// flow pair + chunk-3 zero tail ride along. grid (256 rows, 4 batches) x 256 thr.
__global__ __launch_bounds__(256) void k_up(const float* __restrict__ bflow,
    const float* __restrict__ bfeat, char* __restrict__ ws){
  const int w = threadIdx.x;                 // px 0..255
  const int bx = blockIdx.x;
  const int bio = blockIdx.y;
  const int h = (bx & 7) * 32 + (bx >> 3);   // XCD swizzle
  int y0 = (h >> 1) - 1 + (h & 1);
  const float fy = (h & 1) ? 0.25f : 0.75f;
  const int y0o = (y0 < 0 ? 0 : y0) * 128;
  const int y1o = ((y0 + 1) > 127 ? 127 : (y0 + 1)) * 128;
  int x0 = (w >> 1) - 1 + (w & 1);
  const float fx = (w & 1) ? 0.25f : 0.75f;
  const int x0c = x0 < 0 ? 0 : x0;
  const int x1c = (x0 + 1) > 127 ? 127 : (x0 + 1);

  char* pxb = ws + OFF_INPT + (size_t)bio * S_INPT + ((size_t)(h + 1) * 258 + (w + 1)) * 64;

  u32 pk[16];
  #pragma unroll
  for (int d = 0; d < 16; d++){
    float vv[2];
    #pragma unroll
    for (int e = 0; e < 2; e++){
      const float* pl = bfeat + ((size_t)(bio * 32 + 2 * d + e)) * 16384;
      float v00 = pl[y0o + x0c], v01 = pl[y0o + x1c];
      float v10 = pl[y1o + x0c], v11 = pl[y1o + x1c];
      float r0 = v00 + fx * (v01 - v00);
      float r1 = v10 + fx * (v11 - v10);
      vv[e] = r0 + fy * (r1 - r0);
    }
    pk[d] = pack2(vv[0], vv[1]);
  }
  uint4* dst0 = (uint4*)pxb;
  #pragma unroll
  for (int q = 0; q < 4; q++) dst0[q] = ((uint4*)pk)[q];

  // flow (ch 32..33 -> chunk1 ch0..1), scaled x2
  float fv[2];
  #pragma unroll
  for (int e = 0; e < 2; e++){
    const float* pl = bflow + ((size_t)(bio * 2 + e)) * 16384;
    float v00 = pl[y0o + x0c], v01 = pl[y0o + x1c];
    float v10 = pl[y1o + x0c], v11 = pl[y1o + x1c];
    float r0 = v00 + fx * (v01 - v00);
    float r1 = v10 + fx * (v11 - v10);
    fv[e] = (r0 + fy * (r1 - r0)) * 2.f;
  }
  *(u32*)(pxb + C_CH) = pack2(fv[0], fv[1]);

  // zero tail: chunk3 ch19..31 (bytes 38..63)
  *(u16*)(pxb + 3 * C_CH + 38) = 0;
  #pragma unroll
  for (int k2 = 0; k2 < 6; k2++) *(u32*)(pxb + 3 * C_CH + 40 + 4 * k2) = 0;
}

// ---------------- MFMA correlation: D[m][n] = sum_c ref[c][w0+m] * nb[c][ih][w0+n-4] ----------
// Per wave: 16 px, all 9 dy x 9 dx. Epilogue: predicated 2B stores into chunk-major inpT.
__global__ __launch_bounds__(256) void k_corr_mfma(const u16* __restrict__ xrefT0,
    const u16* __restrict__ xnbT0, char* __restrict__ ws){
  const int tid = threadIdx.x;
  const int wv = tid >> 6, l = tid & 63;
  const int bx = blockIdx.x;
  const int bio = blockIdx.y;
  const u16* xrefT = xrefT0 + (size_t)bio * SE_XREF;
  const u16* xnbT  = xnbT0  + (size_t)bio * SE_XNB;
  const int r = bx & 255, sub = bx >> 8;
  const int h = (r & 7) * 32 + (r >> 3);     // XCD swizzle: nbT row reuse stays on-XCD
  const int w0 = (sub * 4 + wv) * 16;
  const int m16 = l & 15, g = l >> 4;

  uint4 ua = *(const uint4*)(xrefT + ((size_t)h * 256 + w0 + m16) * 32 + g * 8);
  bf16x8 av = __builtin_bit_cast(bf16x8, ua);

  size_t bOff = ((size_t)h * 272 + w0 + m16) * 32 + g * 8;
  char* ob = ws + OFF_INPT + (size_t)bio * S_INPT
             + ((size_t)(h + 1) * 258 + (w0 + 1) + g * 4) * 64;
  const f32x4 z = {0.f, 0.f, 0.f, 0.f};
  #pragma unroll
  for (int dy = 0; dy < 9; dy++){
    uint4 ub0 = *(const uint4*)(xnbT + bOff);
    uint4 ub1 = *(const uint4*)(xnbT + bOff + 512);
    bOff += 8704;                            // next padded row (272*32)
    f32x4 d0 = __builtin_amdgcn_mfma_f32_16x16x32_bf16(av, __builtin_bit_cast(bf16x8, ub0), z, 0, 0, 0);
    f32x4 d1 = __builtin_amdgcn_mfma_f32_16x16x32_bf16(av, __builtin_bit_cast(bf16x8, ub1), z, 0, 0, 0);
    #pragma unroll
    for (int j = 0; j < 4; j++){
      int dxa = m16 - g * 4 - j;             // frag0: dx = n - m
      int dxb = dxa + 16;                    // frag1: dx = n + 16 - m
      bool va = (unsigned)dxa <= 8u;
      bool vb = (unsigned)dxb <= 8u;
      if (va | vb){
        float val = va ? d0[j] : d1[j];
        int dx = va ? dxa : dxb;
        float f = lrelu(val * 0.03125f);
        int c = 34 + dy * 9 + dx;            // chunk-major channel
        *(u16*)(ob + j * 64 + (size_t)(c >> 5) * C_CH + (c & 31) * 2) = f2bf(f);
      }
    }
  }
}

// ---------------- conv0: 128->32, LDS-staged input (s-chunked), weights from global(L2) ------
// R14: block = 4 out rows x 128 px, 4 waves (wave = 1 row). Per s-chunk: stage [6 rows][130 px][32ch]
// (49.9 KB LDS, 3 blocks/CU), each input byte read from HBM exactly once per block.
__global__ __launch_bounds__(256) void k_conv0(const u16* __restrict__ inT0, const u16* __restrict__ wt,
    const float* __restrict__ bias, u16* __restrict__ outA0){
  __shared__ __align__(16) u16 inL[24960];       // [6][130][32]
  const int tid = threadIdx.x;
  const int bx = blockIdx.x;
  const int bio = blockIdx.y;
  const u16* inT = inT0 + (size_t)bio * SE_INPT;
  u16* outA = outA0 + (size_t)bio * SE_H;
  const int rq = (bx & 7) * 8 + ((bx >> 3) & 7); // row-quad 0..63, XCD-banded
  const int ph = bx >> 6;                        // px half
  const int row0 = rq * 4, p0 = ph * 128;
  const int wv = tid >> 6, ln = tid & 63, l15 = ln & 15, l4 = ln >> 4;
  f32x4 acc[8][2] = {};

  for (int s = 0; s < 4; s++){
    // stage input chunk s: halo rows row0..row0+5, halo px p0..p0+129 (each byte once)
    for (int i = tid; i < 3120; i += 256){
      int rr = i / 520, q = i - rr * 520;
      int pxi = q >> 2, cq = q & 3;
      const u16* src = inT + ((size_t)s * 66564 + (size_t)(row0 + rr) * 258 + (p0 + pxi)) * 32 + cq * 8;
      ((uint4*)inL)[(rr * 130 + pxi) * 4 + cq] = *(const uint4*)src;
    }
    __syncthreads();
    #pragma unroll
    for (int ky = 0; ky < 3; ky++){
      #pragma unroll
      for (int kx = 0; kx < 3; kx++){
        const int tap = ky * 3 + kx;
        bf16x8 bv[2];
        #pragma unroll
        for (int j = 0; j < 2; j++){
          uint4 u = *(const uint4*)(wt + (size_t)(j * 16 + l15) * 1160 + tap * 128 + s * 32 + l4 * 8);
          bv[j] = __builtin_bit_cast(bf16x8, u);
        }
        #pragma unroll
        for (int t = 0; t < 8; t++){
          uint4 uai = *(const uint4*)&inL[((wv + ky) * 130 + t * 16 + l15 + kx) * 32 + l4 * 8];
          bf16x8 av = __builtin_bit_cast(bf16x8, uai);
          #pragma unroll
          for (int j = 0; j < 2; j++)
            acc[t][j] = __builtin_amdgcn_mfma_f32_16x16x32_bf16(av, bv[j], acc[t][j], 0, 0, 0);
        }
      }
    }
    __syncthreads();
  }
  // epilogue: wave wv owns out row row0+wv; bias + lrelu -> hT halo layout
  const int row = row0 + wv;
  #pragma unroll
  for (int t = 0; t < 8; t++){
    const int pxb = p0 + t * 16 + l4 * 4;
    #pragma unroll
    for (int j = 0; j < 2; j++){
      const int co = j * 16 + l15;
      const float bs = bias[co];
      #pragma unroll
      for (int r = 0; r < 4; r++){
        const int px = pxb + r;
        float v = lrelu(acc[t][j][r] + bs);
        outA[(size_t)((row + 1) * HP + px + 1) * 32 + co] = f2bf(v);
      }
    }
  }
}

// ---------------- 32-cin convs (conv1/conv2/convf), LDS-staged input, global weights ---------
// R14: block = 4 out rows x 128 px, 4 waves. Stage [6][130][32] once (49.9 KB), weights from L2.
// MODE 0: bias+lrelu -> halo outH (t1). MODE 1: +resid, lrelu -> halo outH (fea) AND fp32 out feats.
// MODE 2: flows (co 0,1) + sigmoid mask (co 2) -> fp32 out.
template<int NT, int MODE>
__global__ __launch_bounds__(256) void k_conv32(const u16* __restrict__ inT0, const u16* __restrict__ wt,
    const float* __restrict__ bias, u16* __restrict__ outH0, float* __restrict__ outF,
    const u16* __restrict__ resid0){
  __shared__ __align__(16) u16 inL[24960];       // [6][130][32]
  const int tid = threadIdx.x;
  const int bx = blockIdx.x;
  const int bio = blockIdx.y;
  const u16* inT = inT0 + (size_t)bio * SE_H;
  const int rq = (bx & 7) * 8 + ((bx >> 3) & 7);
  const int ph = bx >> 6;
  const int row0 = rq * 4, p0 = ph * 128;
  const int wv = tid >> 6, ln = tid & 63, l15 = ln & 15, l4 = ln >> 4;

  for (int i = tid; i < 3120; i += 256){
    int rr = i / 520, q = i - rr * 520;
    int pxi = q >> 2, cq = q & 3;
    const u16* src = inT + ((size_t)(row0 + rr) * 258 + (p0 + pxi)) * 32 + cq * 8;
    ((uint4*)inL)[(rr * 130 + pxi) * 4 + cq] = *(const uint4*)src;
  }
  __syncthreads();

  f32x4 acc[8][NT] = {};
  #pragma unroll
  for (int ky = 0; ky < 3; ky++){
    #pragma unroll
    for (int kx = 0; kx < 3; kx++){
      const int tap = ky * 3 + kx;
      bf16x8 bv[NT];
      #pragma unroll
      for (int j = 0; j < NT; j++){
        uint4 u = *(const uint4*)(wt + (size_t)(j * 16 + l15) * 296 + tap * 32 + l4 * 8);
        bv[j] = __builtin_bit_cast(bf16x8, u);
      }
      #pragma unroll
      for (int t = 0; t < 8; t++){
        uint4 uai = *(const uint4*)&inL[((wv + ky) * 130 + t * 16 + l15 + kx) * 32 + l4 * 8];
        bf16x8 av = __builtin_bit_cast(bf16x8, uai);
        #pragma unroll
        for (int j = 0; j < NT; j++)
          acc[t][j] = __builtin_amdgcn_mfma_f32_16x16x32_bf16(av, bv[j], acc[t][j], 0, 0, 0);
      }
    }
  }
  const int row = row0 + wv;
  #pragma unroll
  for (int t = 0; t < 8; t++){
    const int pxb = p0 + t * 16 + l4 * 4;
    #pragma unroll
    for (int j = 0; j < NT; j++){
      const int co = j * 16 + l15;
      float bs;
      if constexpr (MODE == 2) bs = (co < 3) ? bias[co] : 0.f;
      else bs = bias[co];
      #pragma unroll
      for (int r = 0; r < 4; r++){
        const int px = pxb + r;
        float v = acc[t][j][r] + bs;
        if constexpr (MODE == 0){
          v = lrelu(v);
          outH0[(size_t)bio * SE_H + (size_t)((row + 1) * HP + px + 1) * 32 + co] = f2bf(v);
        } else if constexpr (MODE == 1){
          float hres = bf2f(resid0[(size_t)bio * SE_H + (size_t)((row + 1) * HP + px + 1) * 32 + co]);
          v = lrelu(v + hres);
          outH0[(size_t)bio * SE_H + (size_t)((row + 1) * HP + px + 1) * 32 + co] = f2bf(v); // feaT
          outF[786432 + ((size_t)(bio * 32 + co)) * 65536 + (size_t)row * 256 + px] = v;     // feats
        } else {
          if (co < 2)
            outF[((size_t)(bio * 2 + co)) * 65536 + (size_t)row * 256 + px] = v;             // flows
          else if (co == 2){
            float s = 1.f / (1.f + __expf(-v));
            outF[524288 + (size_t)bio * 65536 + (size_t)row * 256 + px] = s;                 // mask
          }
        }
      }
    }
  }
}

extern "C" void kernel_launch(void* const* d_in, const int* in_sizes, int n_in,
                              void* d_out, int out_size, void* d_ws, size_t ws_size,
                              hipStream_t stream){
  float* out = (float*)d_out;

  // ---- runtime interface verification (kept from R6; encodes any mismatch into out[0]) ----
  static const int exp_sizes[12] = {8388608, 8388608, 131072, 2097152,
                                    33120, 32, 9216, 32, 9216, 32, 864, 3};
  float sent = 0.f;
  if (n_in != 12) sent = 1.0e6f;
  else if (out_size != 9175040) sent = 2.0e6f;
  else {
    for (int i = 0; i < 12; i++)
      if (in_sizes[i] != exp_sizes[i]){ sent = 3.0e6f * (1.0f + 0.01f * i); break; }
    if (sent == 0.f && ws_size < WS_NEED)
      sent = 16.0f * (float)(ws_size >> 20);
  }
  if (sent != 0.f){
    hipLaunchKernelGGL(k_sent, dim3(1), dim3(64), 0, stream, out, sent);
    return;
  }

  const float* xref  = (const float*)d_in[0];
  const float* xnb   = (const float*)d_in[1];
  const float* bflow = (const float*)d_in[2];
  const float* bfeat = (const float*)d_in[3];
  const float* w0 = (const float*)d_in[4];
  const float* b0 = (const float*)d_in[5];
  const float* w1 = (const float*)d_in[6];
  const float* b1 = (const float*)d_in[7];
  const float* w2 = (const float*)d_in[8];
  const float* b2 = (const float*)d_in[9];
  const float* wf = (const float*)d_in[10];
  const float* bf = (const float*)d_in[11];
  char* ws = (char*)d_ws;
  u16* wse   = (u16*)d_ws;
  u16* inpT  = (u16*)(ws + OFF_INPT);
  u16* hT    = (u16*)(ws + OFF_HT);
  u16* t1T   = (u16*)(ws + OFF_T1);
  u16* feaT  = (u16*)(ws + OFF_FEA);
  u16* xrefT = (u16*)(ws + OFF_XREFT);
  u16* xnbT  = (u16*)(ws + OFF_XNBT);

  hipLaunchKernelGGL(k_halo, dim3(261, 4), dim3(256), 0, stream, ws);
  hipLaunchKernelGGL(k_wprep, dim3(64), dim3(256), 0, stream, w0, w1, w2, wf, wse);
  hipLaunchKernelGGL(k_xpose, dim3(520, 4), dim3(320), 0, stream, xref, xnb, xrefT, xnbT);
  hipLaunchKernelGGL(k_up, dim3(256, 4), dim3(256), 0, stream, bflow, bfeat, ws);
  hipLaunchKernelGGL(k_corr_mfma, dim3(1024, 4), dim3(256), 0, stream, xrefT, xnbT, ws);
  hipLaunchKernelGGL(k_conv0, dim3(128, 4), dim3(256), 0, stream, inpT, wse + E_WT0, b0, hT);
  hipLaunchKernelGGL((k_conv32<2, 0>), dim3(128, 4), dim3(256), 0, stream,
                     hT, wse + E_WT1, b1, t1T, (float*)nullptr, (const u16*)nullptr);
  hipLaunchKernelGGL((k_conv32<2, 1>), dim3(128, 4), dim3(256), 0, stream,
                     t1T, wse + E_WT2, b2, feaT, out, hT);
  hipLaunchKernelGGL((k_conv32<1, 2>), dim3(128, 4), dim3(256), 0, stream,
                     feaT, wse + E_WTF, bf, (u16*)nullptr, out, (const u16*)nullptr);
}

// Round 8
// 289.550 us; speedup vs baseline: 2.5187x; 1.0185x over previous
//
#include <hip/hip_runtime.h>

typedef unsigned short u16;
typedef unsigned int u32;
typedef __bf16 bf16x8 __attribute__((ext_vector_type(8)));
typedef float f32x4 __attribute__((ext_vector_type(4)));

#define HP 258
// weight-table element offsets within ws (u16 units)
#define E_WT0 0
#define E_WT1 37120
#define E_WT2 46592
#define E_WTF 56064
// ---- per-batch strided layout: all 4 batches resident simultaneously ----
// 258*258 = 66564 pixels. R14: inpT is CHUNK-MAJOR [4 ch-chunks][66564 px][32 ch] bf16.
#define C_CH      4260096ull             // one chunk = 66564*32*2 B
#define OFF_INPT  131072ull
#define S_INPT    17040384ull            // 4*C_CH
#define OFF_HT    68292608ull            // OFF_INPT + 4*S_INPT
#define S_H       4260096ull             // 66564*32*2
#define OFF_T1    85332992ull            // OFF_HT + 4*S_H
#define OFF_FEA   102373376ull           // OFF_T1 + 4*S_H
#define OFF_XREFT 119413760ull           // OFF_FEA + 4*S_H
#define S_XREF    4194304ull             // 256*256*32*2
#define OFF_XNBT  136190976ull           // OFF_XREFT + 4*S_XREF
#define S_XNB     4595712ull             // 264*272*32*2
#define WS_NEED   154573824ull           // OFF_XNBT + 4*S_XNB  (ws is 256 MiB per R2 fill evidence)
// u16-element strides
#define SE_INPT 8520192u
#define SE_H    2130048u
#define SE_XREF 2097152u
#define SE_XNB  2297856u

__device__ __forceinline__ float bf2f(u16 u){ u32 x = ((u32)u) << 16; return __builtin_bit_cast(float, x); }
__device__ __forceinline__ u16 f2bf(float f){
  u32 x = __builtin_bit_cast(u32, f);
  return (u16)((x + 0x7fffu + ((x >> 16) & 1u)) >> 16);   // RNE
}
__device__ __forceinline__ u32 pack2(float a, float b){ return (u32)f2bf(a) | ((u32)f2bf(b) << 16); }
__device__ __forceinline__ float lrelu(float x){ return x >= 0.f ? x : 0.1f * x; }

__global__ void k_sent(float* __restrict__ out, float val){
  if (threadIdx.x == 0 && blockIdx.x == 0) out[0] = val;
}

// ---------------- halo-ring zeroing for all four per-batch buffer sets (once per launch) ------
__global__ __launch_bounds__(256) void k_halo(char* __restrict__ ws){
  int idx = blockIdx.x * 256 + threadIdx.x;
  const int bio = blockIdx.y;
  if (idx >= 258 * 258) return;
  int y = idx / 258;
  int x = idx - y * 258;
  if (y != 0 && y != 257 && x != 0 && x != 257) return;
  uint4 z = make_uint4(0u, 0u, 0u, 0u);
  size_t pix = (size_t)idx;
  #pragma unroll
  for (int s = 0; s < 4; s++){
    uint4* p0 = (uint4*)(ws + OFF_INPT + (size_t)bio * S_INPT + (size_t)s * C_CH + pix * 64);
    #pragma unroll
    for (int k = 0; k < 4; k++) p0[k] = z;
  }
  uint4* p1 = (uint4*)(ws + OFF_HT  + (size_t)bio * S_H + pix * 64);
  uint4* p2 = (uint4*)(ws + OFF_T1  + (size_t)bio * S_H + pix * 64);
  uint4* p3 = (uint4*)(ws + OFF_FEA + (size_t)bio * S_H + pix * 64);
  #pragma unroll
  for (int k = 0; k < 4; k++){ p1[k] = z; p2[k] = z; p3[k] = z; }
}

// ---------------- weight re-layout: Wt[co][tap*Cpad + c], tap-major K, channel-permuted -------
// inpT channel order: 0..31 up-feat, 32..33 flow, 34..114 corr(dy*9+dx), 115..127 zero.
// Original (R8-verified) w0 input-channel order: 0..80 corr, 81..112 feat, 113..114 flow.
__global__ __launch_bounds__(256) void k_wprep(const float* __restrict__ w0, const float* __restrict__ w1,
    const float* __restrict__ w2, const float* __restrict__ wf, u16* __restrict__ wse){
  for (int idx = blockIdx.x * 256 + threadIdx.x; idx < 60800; idx += 64 * 256){
    float v = 0.f;
    if (idx < 37120){                       // Wt0: 32 rows x 1160 (K=9*128=1152 used)
      int co = idx / 1160, kk = idx % 1160;
      if (kk < 1152){
        int tap = kk >> 7, c = kk & 127;
        if (c < 115){
          int oc = (c < 34) ? (81 + c) : (c - 34);
          v = w0[(co * 115 + oc) * 9 + tap];
        }
      }
    } else if (idx < 46592){                // Wt1: 32 x 296 (K=9*32=288)
      int r = idx - 37120; int co = r / 296, kk = r % 296;
      if (kk < 288){ int tap = kk >> 5, c = kk & 31; v = w1[(co * 32 + c) * 9 + tap]; }
    } else if (idx < 56064){                // Wt2
      int r = idx - 46592; int co = r / 296, kk = r % 296;
      if (kk < 288){ int tap = kk >> 5, c = kk & 31; v = w2[(co * 32 + c) * 9 + tap]; }
    } else {                                // Wtf: 16 x 296, rows 3..15 zero
      int r = idx - 56064; int co = r / 296, kk = r % 296;
      if (kk < 288 && co < 3){ int tap = kk >> 5, c = kk & 31; v = wf[(co * 32 + c) * 9 + tap]; }
    }
    wse[idx] = f2bf(v);
  }
}

// ---------------- transpose prepass: [c][h][w] fp32 -> [h][w][c] bf16 -------------------------
// R16: 4 threads/px, 8 ch/thread (8 independent loads, 16 B store). 64-thr blocks.
// blocks 0..4095: xrefT (row = bx>>4, 16 px per block). blocks 4096..8583: xnbT padded
// (rows -4..259, px -4..267; 17 groups of 16 px per row).
__global__ __launch_bounds__(64) void k_xpose(const float* __restrict__ xref,
    const float* __restrict__ xnb, u16* __restrict__ xrefT0, u16* __restrict__ xnbT0){
  const int l = threadIdx.x;
  const int bxx = blockIdx.x;
  const int bio = blockIdx.y;
  const int cq = l & 3, c0 = cq * 8;
  float v[8];
  u32 p[4];
  if (bxx < 4096){
    const int row = bxx >> 4;
    const int px = ((bxx & 15) << 4) + (l >> 2);
    const float* src = xref + ((size_t)(bio * 32 + c0)) * 65536 + (size_t)row * 256 + px;
    #pragma unroll
    for (int k = 0; k < 8; k++) v[k] = src[(size_t)k * 65536];
    #pragma unroll
    for (int j = 0; j < 4; j++) p[j] = pack2(v[2 * j], v[2 * j + 1]);
    *(uint4*)(xrefT0 + (size_t)bio * SE_XREF + ((size_t)row * 256 + px) * 32 + c0) = *(uint4*)p;
  } else {
    const int i = bxx - 4096;
    const int hp = i / 17, pg = i - hp * 17;
    const int pt = pg * 16 + (l >> 2);
    const int ih = hp - 4, px = pt - 4;
    u16* dst = xnbT0 + (size_t)bio * SE_XNB + ((size_t)hp * 272 + pt) * 32 + c0;
    if (ih >= 0 && ih <= 255 && px >= 0 && px <= 255){
      const float* src = xnb + ((size_t)(bio * 32 + c0)) * 65536 + (size_t)ih * 256 + px;
      #pragma unroll
      for (int k = 0; k < 8; k++) v[k] = src[(size_t)k * 65536];
      #pragma unroll
      for (int j = 0; j < 4; j++) p[j] = pack2(v[2 * j], v[2 * j + 1]);
      *(uint4*)dst = *(uint4*)p;
    } else {
      uint4 z = make_uint4(0u, 0u, 0u, 0u);
      *(uint4*)dst = z;
    }
  }
}

// ---------------- bilinear 2x upsample: thread = 1 px, ALL 34 channels -----------------------
// R15: chunk-0 (ch0..31) written as one contiguous 64 B line per thread (wave = 4 KB / instr);
// flow pair + chunk-3 zero tail ride along. grid (256 rows, 4 batches) x 256 thr.
__global__ __launch_bounds__(256) void k_up(const float* __restrict__ bflow,
    const float* __restrict__ bfeat, char* __restrict__ ws){
  const int w = threadIdx.x;                 // px 0..255
  const int bx = blockIdx.x;
  const int bio = blockIdx.y;
  const int h = (bx & 7) * 32 + (bx >> 3);   // XCD swizzle
  int y0 = (h >> 1) - 1 + (h & 1);
  const float fy = (h & 1) ? 0.25f : 0.75f;
  const int y0o = (y0 < 0 ? 0 : y0) * 128;
  const int y1o = ((y0 + 1) > 127 ? 127 : (y0 + 1)) * 128;
  int x0 = (w >> 1) - 1 + (w & 1);
  const float fx = (w & 1) ? 0.25f : 0.75f;
  const int x0c = x0 < 0 ? 0 : x0;
  const int x1c = (x0 + 1) > 127 ? 127 : (x0 + 1);

  char* pxb = ws + OFF_INPT + (size_t)bio * S_INPT + ((size_t)(h + 1) * 258 + (w + 1)) * 64;

  u32 pk[16];
  #pragma unroll
  for (int d = 0; d < 16; d++){
    float vv[2];
    #pragma unroll
    for (int e = 0; e < 2; e++){
      const float* pl = bfeat + ((size_t)(bio * 32 + 2 * d + e)) * 16384;
      float v00 = pl[y0o + x0c], v01 = pl[y0o + x1c];
      float v10 = pl[y1o + x0c], v11 = pl[y1o + x1c];
      float r0 = v00 + fx * (v01 - v00);
      float r1 = v10 + fx * (v11 - v10);
      vv[e] = r0 + fy * (r1 - r0);
    }
    pk[d] = pack2(vv[0], vv[1]);
  }
  uint4* dst0 = (uint4*)pxb;
  #pragma unroll
  for (int q = 0; q < 4; q++) dst0[q] = ((uint4*)pk)[q];

  // flow (ch 32..33 -> chunk1 ch0..1), scaled x2
  float fv[2];
  #pragma unroll
  for (int e = 0; e < 2; e++){
    const float* pl = bflow + ((size_t)(bio * 2 + e)) * 16384;
    float v00 = pl[y0o + x0c], v01 = pl[y0o + x1c];
    float v10 = pl[y1o + x0c], v11 = pl[y1o + x1c];
    float r0 = v00 + fx * (v01 - v00);
    float r1 = v10 + fx * (v11 - v10);
    fv[e] = (r0 + fy * (r1 - r0)) * 2.f;
  }
  *(u32*)(pxb + C_CH) = pack2(fv[0], fv[1]);

  // zero tail: chunk3 ch19..31 (bytes 38..63)
  *(u16*)(pxb + 3 * C_CH + 38) = 0;
  #pragma unroll
  for (int k2 = 0; k2 < 6; k2++) *(u32*)(pxb + 3 * C_CH + 40 + 4 * k2) = 0;
}

// ---------------- MFMA correlation: D[m][n] = sum_c ref[c][w0+m] * nb[c][ih][w0+n-4] ----------
// Per wave: 16 px, all 9 dy x 9 dx. Epilogue: predicated 2B stores into chunk-major inpT.
__global__ __launch_bounds__(256) void k_corr_mfma(const u16* __restrict__ xrefT0,
    const u16* __restrict__ xnbT0, char* __restrict__ ws){
  const int tid = threadIdx.x;
  const int wv = tid >> 6, l = tid & 63;
  const int bx = blockIdx.x;
  const int bio = blockIdx.y;
  const u16* xrefT = xrefT0 + (size_t)bio * SE_XREF;
  const u16* xnbT  = xnbT0  + (size_t)bio * SE_XNB;
  const int r = bx & 255, sub = bx >> 8;
  const int h = (r & 7) * 32 + (r >> 3);     // XCD swizzle: nbT row reuse stays on-XCD
  const int w0 = (sub * 4 + wv) * 16;
  const int m16 = l & 15, g = l >> 4;

  uint4 ua = *(const uint4*)(xrefT + ((size_t)h * 256 + w0 + m16) * 32 + g * 8);
  bf16x8 av = __builtin_bit_cast(bf16x8, ua);

  size_t bOff = ((size_t)h * 272 + w0 + m16) * 32 + g * 8;
  char* ob = ws + OFF_INPT + (size_t)bio * S_INPT
             + ((size_t)(h + 1) * 258 + (w0 + 1) + g * 4) * 64;
  const f32x4 z = {0.f, 0.f, 0.f, 0.f};
  #pragma unroll
  for (int dy = 0; dy < 9; dy++){
    uint4 ub0 = *(const uint4*)(xnbT + bOff);
    uint4 ub1 = *(const uint4*)(xnbT + bOff + 512);
    bOff += 8704;                            // next padded row (272*32)
    f32x4 d0 = __builtin_amdgcn_mfma_f32_16x16x32_bf16(av, __builtin_bit_cast(bf16x8, ub0), z, 0, 0, 0);
    f32x4 d1 = __builtin_amdgcn_mfma_f32_16x16x32_bf16(av, __builtin_bit_cast(bf16x8, ub1), z, 0, 0, 0);
    #pragma unroll
    for (int j = 0; j < 4; j++){
      int dxa = m16 - g * 4 - j;             // frag0: dx = n - m
      int dxb = dxa + 16;                    // frag1: dx = n + 16 - m
      bool va = (unsigned)dxa <= 8u;
      bool vb = (unsigned)dxb <= 8u;
      if (va | vb){
        float val = va ? d0[j] : d1[j];
        int dx = va ? dxa : dxb;
        float f = lrelu(val * 0.03125f);
        int c = 34 + dy * 9 + dx;            // chunk-major channel
        *(u16*)(ob + j * 64 + (size_t)(c >> 5) * C_CH + (c & 31) * 2) = f2bf(f);
      }
    }
  }
}

// ---------------- conv0: 128->32, LDS-staged input (s-chunked), weights from global(L2) ------
// R14: block = 4 out rows x 128 px, 4 waves (wave = 1 row). Per s-chunk: stage [6 rows][130 px][32ch]
// (49.9 KB LDS, 3 blocks/CU), each input byte read from HBM exactly once per block.
__global__ __launch_bounds__(256) void k_conv0(const u16* __restrict__ inT0, const u16* __restrict__ wt,
    const float* __restrict__ bias, u16* __restrict__ outA0){
  __shared__ __align__(16) u16 inL[24960];       // [6][130][32]
  const int tid = threadIdx.x;
  const int bx = blockIdx.x;
  const int bio = blockIdx.y;
  const u16* inT = inT0 + (size_t)bio * SE_INPT;
  u16* outA = outA0 + (size_t)bio * SE_H;
  const int rq = (bx & 7) * 8 + ((bx >> 3) & 7); // row-quad 0..63, XCD-banded
  const int ph = bx >> 6;                        // px half
  const int row0 = rq * 4, p0 = ph * 128;
  const int wv = tid >> 6, ln = tid & 63, l15 = ln & 15, l4 = ln >> 4;
  f32x4 acc[8][2] = {};

  for (int s = 0; s < 4; s++){
    // stage input chunk s: halo rows row0..row0+5, halo px p0..p0+129 (each byte once)
    for (int i = tid; i < 3120; i += 256){
      int rr = i / 520, q = i - rr * 520;
      int pxi = q >> 2, cq = q & 3;
      const u16* src = inT + ((size_t)s * 66564 + (size_t)(row0 + rr) * 258 + (p0 + pxi)) * 32 + cq * 8;
      ((uint4*)inL)[(rr * 130 + pxi) * 4 + cq] = *(const uint4*)src;
    }
    __syncthreads();
    #pragma unroll
    for (int ky = 0; ky < 3; ky++){
      #pragma unroll
      for (int kx = 0; kx < 3; kx++){
        const int tap = ky * 3 + kx;
        bf16x8 bv[2];
        #pragma unroll
        for (int j = 0; j < 2; j++){
          uint4 u = *(const uint4*)(wt + (size_t)(j * 16 + l15) * 1160 + tap * 128 + s * 32 + l4 * 8);
          bv[j] = __builtin_bit_cast(bf16x8, u);
        }
        #pragma unroll
        for (int t = 0; t < 8; t++){
          uint4 uai = *(const uint4*)&inL[((wv + ky) * 130 + t * 16 + l15 + kx) * 32 + l4 * 8];
          bf16x8 av = __builtin_bit_cast(bf16x8, uai);
          #pragma unroll
          for (int j = 0; j < 2; j++)
            acc[t][j] = __builtin_amdgcn_mfma_f32_16x16x32_bf16(av, bv[j], acc[t][j], 0, 0, 0);
        }
      }
    }
    __syncthreads();
  }
  // epilogue: wave wv owns out row row0+wv; bias + lrelu -> hT halo layout
  const int row = row0 + wv;
  #pragma unroll
  for (int t = 0; t < 8; t++){
    const int pxb = p0 + t * 16 + l4 * 4;
    #pragma unroll
    for (int j = 0; j < 2; j++){
      const int co = j * 16 + l15;
      const float bs = bias[co];
      #pragma unroll
      for (int r = 0; r < 4; r++){
        const int px = pxb + r;
        float v = lrelu(acc[t][j][r] + bs);
        outA[(size_t)((row + 1) * HP + px + 1) * 32 + co] = f2bf(v);
      }
    }
  }
}

// ---------------- 32-cin convs (conv1/conv2/convf), LDS-staged input, global weights ---------
// R14: block = 4 out rows x 128 px, 4 waves. Stage [6][130][32] once (49.9 KB), weights from L2.
// MODE 0: bias+lrelu -> halo outH (t1). MODE 1: +resid, lrelu -> halo outH (fea) AND fp32 out feats.
// MODE 2: flows (co 0,1) + sigmoid mask (co 2) -> fp32 out.
template<int NT, int MODE>
__global__ __launch_bounds__(256) void k_conv32(const u16* __restrict__ inT0, const u16* __restrict__ wt,
    const float* __restrict__ bias, u16* __restrict__ outH0, float* __restrict__ outF,
    const u16* __restrict__ resid0){
  __shared__ __align__(16) u16 inL[24960];       // [6][130][32]
  const int tid = threadIdx.x;
  const int bx = blockIdx.x;
  const int bio = blockIdx.y;
  const u16* inT = inT0 + (size_t)bio * SE_H;
  const int rq = (bx & 7) * 8 + ((bx >> 3) & 7);
  const int ph = bx >> 6;
  const int row0 = rq * 4, p0 = ph * 128;
  const int wv = tid >> 6, ln = tid & 63, l15 = ln & 15, l4 = ln >> 4;

  for (int i = tid; i < 3120; i += 256){
    int rr = i / 520, q = i - rr * 520;
    int pxi = q >> 2, cq = q & 3;
    const u16* src = inT + ((size_t)(row0 + rr) * 258 + (p0 + pxi)) * 32 + cq * 8;
    ((uint4*)inL)[(rr * 130 + pxi) * 4 + cq] = *(const uint4*)src;
  }
  __syncthreads();

  f32x4 acc[8][NT] = {};
  #pragma unroll
  for (int ky = 0; ky < 3; ky++){
    #pragma unroll
    for (int kx = 0; kx < 3; kx++){
      const int tap = ky * 3 + kx;
      bf16x8 bv[NT];
      #pragma unroll
      for (int j = 0; j < NT; j++){
        uint4 u = *(const uint4*)(wt + (size_t)(j * 16 + l15) * 296 + tap * 32 + l4 * 8);
        bv[j] = __builtin_bit_cast(bf16x8, u);
      }
      #pragma unroll
      for (int t = 0; t < 8; t++){
        uint4 uai = *(const uint4*)&inL[((wv + ky) * 130 + t * 16 + l15 + kx) * 32 + l4 * 8];
        bf16x8 av = __builtin_bit_cast(bf16x8, uai);
        #pragma unroll
        for (int j = 0; j < NT; j++)
          acc[t][j] = __builtin_amdgcn_mfma_f32_16x16x32_bf16(av, bv[j], acc[t][j], 0, 0, 0);
      }
    }
  }
  const int row = row0 + wv;
  #pragma unroll
  for (int t = 0; t < 8; t++){
    const int pxb = p0 + t * 16 + l4 * 4;
    #pragma unroll
    for (int j = 0; j < NT; j++){
      const int co = j * 16 + l15;
      float bs;
      if constexpr (MODE == 2) bs = (co < 3) ? bias[co] : 0.f;
      else bs = bias[co];
      #pragma unroll
      for (int r = 0; r < 4; r++){
        const int px = pxb + r;
        float v = acc[t][j][r] + bs;
        if constexpr (MODE == 0){
          v = lrelu(v);
          outH0[(size_t)bio * SE_H + (size_t)((row + 1) * HP + px + 1) * 32 + co] = f2bf(v);
        } else if constexpr (MODE == 1){
          float hres = bf2f(resid0[(size_t)bio * SE_H + (size_t)((row + 1) * HP + px + 1) * 32 + co]);
          v = lrelu(v + hres);
          outH0[(size_t)bio * SE_H + (size_t)((row + 1) * HP + px + 1) * 32 + co] = f2bf(v); // feaT
          outF[786432 + ((size_t)(bio * 32 + co)) * 65536 + (size_t)row * 256 + px] = v;     // feats
        } else {
          if (co < 2)
            outF[((size_t)(bio * 2 + co)) * 65536 + (size_t)row * 256 + px] = v;             // flows
          else if (co == 2){
            float s = 1.f / (1.f + __expf(-v));
            outF[524288 + (size_t)bio * 65536 + (size_t)row * 256 + px] = s;                 // mask
          }
        }
      }
    }
  }
}

extern "C" void kernel_launch(void* const* d_in, const int* in_sizes, int n_in,
                              void* d_out, int out_size, void* d_ws, size_t ws_size,
                              hipStream_t stream){
  float* out = (float*)d_out;

  // ---- runtime interface verification (kept from R6; encodes any mismatch into out[0]) ----
  static const int exp_sizes[12] = {8388608, 8388608, 131072, 2097152,
                                    33120, 32, 9216, 32, 9216, 32, 864, 3};
  float sent = 0.f;
  if (n_in != 12) sent = 1.0e6f;
  else if (out_size != 9175040) sent = 2.0e6f;
  else {
    for (int i = 0; i < 12; i++)
      if (in_sizes[i] != exp_sizes[i]){ sent = 3.0e6f * (1.0f + 0.01f * i); break; }
    if (sent == 0.f && ws_size < WS_NEED)
      sent = 16.0f * (float)(ws_size >> 20);
  }
  if (sent != 0.f){
    hipLaunchKernelGGL(k_sent, dim3(1), dim3(64), 0, stream, out, sent);
    return;
  }

  const float* xref  = (const float*)d_in[0];
  const float* xnb   = (const float*)d_in[1];
  const float* bflow = (const float*)d_in[2];
  const float* bfeat = (const float*)d_in[3];
  const float* w0 = (const float*)d_in[4];
  const float* b0 = (const float*)d_in[5];
  const float* w1 = (const float*)d_in[6];
  const float* b1 = (const float*)d_in[7];
  const float* w2 = (const float*)d_in[8];
  const float* b2 = (const float*)d_in[9];
  const float* wf = (const float*)d_in[10];
  const float* bf = (const float*)d_in[11];
  char* ws = (char*)d_ws;
  u16* wse   = (u16*)d_ws;
  u16* inpT  = (u16*)(ws + OFF_INPT);
  u16* hT    = (u16*)(ws + OFF_HT);
  u16* t1T   = (u16*)(ws + OFF_T1);
  u16* feaT  = (u16*)(ws + OFF_FEA);
  u16* xrefT = (u16*)(ws + OFF_XREFT);
  u16* xnbT  = (u16*)(ws + OFF_XNBT);

  hipLaunchKernelGGL(k_halo, dim3(261, 4), dim3(256), 0, stream, ws);
  hipLaunchKernelGGL(k_wprep, dim3(64), dim3(256), 0, stream, w0, w1, w2, wf, wse);
  hipLaunchKernelGGL(k_xpose, dim3(8584, 4), dim3(64), 0, stream, xref, xnb, xrefT, xnbT);
  hipLaunchKernelGGL(k_up, dim3(256, 4), dim3(256), 0, stream, bflow, bfeat, ws);
  hipLaunchKernelGGL(k_corr_mfma, dim3(1024, 4), dim3(256), 0, stream, xrefT, xnbT, ws);
  hipLaunchKernelGGL(k_conv0, dim3(128, 4), dim3(256), 0, stream, inpT, wse + E_WT0, b0, hT);
  hipLaunchKernelGGL((k_conv32<2, 0>), dim3(128, 4), dim3(256), 0, stream,
                     hT, wse + E_WT1, b1, t1T, (float*)nullptr, (const u16*)nullptr);
  hipLaunchKernelGGL((k_conv32<2, 1>), dim3(128, 4), dim3(256), 0, stream,
                     t1T, wse + E_WT2, b2, feaT, out, hT);
  hipLaunchKernelGGL((k_conv32<1, 2>), dim3(128, 4), dim3(256), 0, stream,
                     feaT, wse + E_WTF, bf, (u16*)nullptr, out, (const u16*)nullptr);
}

// Round 9
// 279.354 us; speedup vs baseline: 2.6106x; 1.0365x over previous
//
#include <hip/hip_runtime.h>

typedef unsigned short u16;
typedef unsigned int u32;
typedef __bf16 bf16x8 __attribute__((ext_vector_type(8)));
typedef float f32x4 __attribute__((ext_vector_type(4)));

#define HP 258
// weight-table element offsets within ws (u16 units)
#define E_WT0 0
#define E_WT1 37120
#define E_WT2 46592
#define E_WTF 56064
// ---- per-batch strided layout: all 4 batches resident simultaneously ----
// 258*258 = 66564 pixels. R14: inpT is CHUNK-MAJOR [4 ch-chunks][66564 px][32 ch] bf16.
#define C_CH      4260096ull             // one chunk = 66564*32*2 B
#define OFF_INPT  131072ull
#define S_INPT    17040384ull            // 4*C_CH
#define OFF_HT    68292608ull            // OFF_INPT + 4*S_INPT
#define S_H       4260096ull             // 66564*32*2
#define OFF_T1    85332992ull            // OFF_HT + 4*S_H
#define OFF_FEA   102373376ull           // OFF_T1 + 4*S_H
#define OFF_XREFT 119413760ull           // OFF_FEA + 4*S_H
#define S_XREF    4194304ull             // 256*256*32*2
#define OFF_XNBT  136190976ull           // OFF_XREFT + 4*S_XREF
#define S_XNB     4595712ull             // 264*272*32*2
#define WS_NEED   154573824ull           // OFF_XNBT + 4*S_XNB  (ws is 256 MiB per R2 fill evidence)
// u16-element strides
#define SE_INPT 8520192u
#define SE_H    2130048u
#define SE_XREF 2097152u
#define SE_XNB  2297856u

__device__ __forceinline__ float bf2f(u16 u){ u32 x = ((u32)u) << 16; return __builtin_bit_cast(float, x); }
__device__ __forceinline__ u16 f2bf(float f){
  u32 x = __builtin_bit_cast(u32, f);
  return (u16)((x + 0x7fffu + ((x >> 16) & 1u)) >> 16);   // RNE
}
__device__ __forceinline__ u32 pack2(float a, float b){ return (u32)f2bf(a) | ((u32)f2bf(b) << 16); }
__device__ __forceinline__ float lrelu(float x){ return x >= 0.f ? x : 0.1f * x; }

__global__ void k_sent(float* __restrict__ out, float val){
  if (threadIdx.x == 0 && blockIdx.x == 0) out[0] = val;
}

// ---------------- halo-ring zeroing for all four per-batch buffer sets (once per launch) ------
__global__ __launch_bounds__(256) void k_halo(char* __restrict__ ws){
  int idx = blockIdx.x * 256 + threadIdx.x;
  const int bio = blockIdx.y;
  if (idx >= 258 * 258) return;
  int y = idx / 258;
  int x = idx - y * 258;
  if (y != 0 && y != 257 && x != 0 && x != 257) return;
  uint4 z = make_uint4(0u, 0u, 0u, 0u);
  size_t pix = (size_t)idx;
  #pragma unroll
  for (int s = 0; s < 4; s++){
    uint4* p0 = (uint4*)(ws + OFF_INPT + (size_t)bio * S_INPT + (size_t)s * C_CH + pix * 64);
    #pragma unroll
    for (int k = 0; k < 4; k++) p0[k] = z;
  }
  uint4* p1 = (uint4*)(ws + OFF_HT  + (size_t)bio * S_H + pix * 64);
  uint4* p2 = (uint4*)(ws + OFF_T1  + (size_t)bio * S_H + pix * 64);
  uint4* p3 = (uint4*)(ws + OFF_FEA + (size_t)bio * S_H + pix * 64);
  #pragma unroll
  for (int k = 0; k < 4; k++){ p1[k] = z; p2[k] = z; p3[k] = z; }
}

// ---------------- weight re-layout: Wt[co][tap*Cpad + c], tap-major K, channel-permuted -------
// inpT channel order: 0..31 up-feat, 32..33 flow, 34..114 corr(dy*9+dx), 115..127 zero.
// Original (R8-verified) w0 input-channel order: 0..80 corr, 81..112 feat, 113..114 flow.
__global__ __launch_bounds__(256) void k_wprep(const float* __restrict__ w0, const float* __restrict__ w1,
    const float* __restrict__ w2, const float* __restrict__ wf, u16* __restrict__ wse){
  for (int idx = blockIdx.x * 256 + threadIdx.x; idx < 60800; idx += 64 * 256){
    float v = 0.f;
    if (idx < 37120){                       // Wt0: 32 rows x 1160 (K=9*128=1152 used)
      int co = idx / 1160, kk = idx % 1160;
      if (kk < 1152){
        int tap = kk >> 7, c = kk & 127;
        if (c < 115){
          int oc = (c < 34) ? (81 + c) : (c - 34);
          v = w0[(co * 115 + oc) * 9 + tap];
        }
      }
    } else if (idx < 46592){                // Wt1: 32 x 296 (K=9*32=288)
      int r = idx - 37120; int co = r / 296, kk = r % 296;
      if (kk < 288){ int tap = kk >> 5, c = kk & 31; v = w1[(co * 32 + c) * 9 + tap]; }
    } else if (idx < 56064){                // Wt2
      int r = idx - 46592; int co = r / 296, kk = r % 296;
      if (kk < 288){ int tap = kk >> 5, c = kk & 31; v = w2[(co * 32 + c) * 9 + tap]; }
    } else {                                // Wtf: 16 x 296, rows 3..15 zero
      int r = idx - 56064; int co = r / 296, kk = r % 296;
      if (kk < 288 && co < 3){ int tap = kk >> 5, c = kk & 31; v = wf[(co * 32 + c) * 9 + tap]; }
    }
    wse[idx] = f2bf(v);
  }
}

// ---------------- transpose prepass: [c][h][w] fp32 -> [h][w][c] bf16 -------------------------
// R16: 4 threads/px, 8 ch/thread (8 independent loads, 16 B store). 64-thr blocks.
__global__ __launch_bounds__(64) void k_xpose(const float* __restrict__ xref,
    const float* __restrict__ xnb, u16* __restrict__ xrefT0, u16* __restrict__ xnbT0){
  const int l = threadIdx.x;
  const int bxx = blockIdx.x;
  const int bio = blockIdx.y;
  const int cq = l & 3, c0 = cq * 8;
  float v[8];
  u32 p[4];
  if (bxx < 4096){
    const int row = bxx >> 4;
    const int px = ((bxx & 15) << 4) + (l >> 2);
    const float* src = xref + ((size_t)(bio * 32 + c0)) * 65536 + (size_t)row * 256 + px;
    #pragma unroll
    for (int k = 0; k < 8; k++) v[k] = src[(size_t)k * 65536];
    #pragma unroll
    for (int j = 0; j < 4; j++) p[j] = pack2(v[2 * j], v[2 * j + 1]);
    *(uint4*)(xrefT0 + (size_t)bio * SE_XREF + ((size_t)row * 256 + px) * 32 + c0) = *(uint4*)p;
  } else {
    const int i = bxx - 4096;
    const int hp = i / 17, pg = i - hp * 17;
    const int pt = pg * 16 + (l >> 2);
    const int ih = hp - 4, px = pt - 4;
    u16* dst = xnbT0 + (size_t)bio * SE_XNB + ((size_t)hp * 272 + pt) * 32 + c0;
    if (ih >= 0 && ih <= 255 && px >= 0 && px <= 255){
      const float* src = xnb + ((size_t)(bio * 32 + c0)) * 65536 + (size_t)ih * 256 + px;
      #pragma unroll
      for (int k = 0; k < 8; k++) v[k] = src[(size_t)k * 65536];
      #pragma unroll
      for (int j = 0; j < 4; j++) p[j] = pack2(v[2 * j], v[2 * j + 1]);
      *(uint4*)dst = *(uint4*)p;
    } else {
      uint4 z = make_uint4(0u, 0u, 0u, 0u);
      *(uint4*)dst = z;
    }
  }
}

// ---------------- bilinear 2x upsample: thread = 1 px, ALL 34 channels -----------------------
// R15: chunk-0 (ch0..31) written as one contiguous 64 B line per thread (wave = 4 KB / instr);
// flow pair + chunk-3 zero tail ride along. grid (256 rows, 4 batches) x 256 thr.
__global__ __launch_bounds__(256) void k_up(const float* __restrict__ bflow,
    const float* __restrict__ bfeat, char* __restrict__ ws){
  const int w = threadIdx.x;                 // px 0..255
  const int bx = blockIdx.x;
  const int bio = blockIdx.y;
  const int h = (bx & 7) * 32 + (bx >> 3);   // XCD swizzle
  int y0 = (h >> 1) - 1 + (h & 1);
  const float fy = (h & 1) ? 0.25f : 0.75f;
  const int y0o = (y0 < 0 ? 0 : y0) * 128;
  const int y1o = ((y0 + 1) > 127 ? 127 : (y0 + 1)) * 128;
  int x0 = (w >> 1) - 1 + (w & 1);
  const float fx = (w & 1) ? 0.25f : 0.75f;
  const int x0c = x0 < 0 ? 0 : x0;
  const int x1c = (x0 + 1) > 127 ? 127 : (x0 + 1);

  char* pxb = ws + OFF_INPT + (size_t)bio * S_INPT + ((size_t)(h + 1) * 258 + (w + 1)) * 64;

  u32 pk[16];
  #pragma unroll
  for (int d = 0; d < 16; d++){
    float vv[2];
    #pragma unroll
    for (int e = 0; e < 2; e++){
      const float* pl = bfeat + ((size_t)(bio * 32 + 2 * d + e)) * 16384;
      float v00 = pl[y0o + x0c], v01 = pl[y0o + x1c];
      float v10 = pl[y1o + x0c], v11 = pl[y1o + x1c];
      float r0 = v00 + fx * (v01 - v00);
      float r1 = v10 + fx * (v11 - v10);
      vv[e] = r0 + fy * (r1 - r0);
    }
    pk[d] = pack2(vv[0], vv[1]);
  }
  uint4* dst0 = (uint4*)pxb;
  #pragma unroll
  for (int q = 0; q < 4; q++) dst0[q] = ((uint4*)pk)[q];

  // flow (ch 32..33 -> chunk1 ch0..1), scaled x2
  float fv[2];
  #pragma unroll
  for (int e = 0; e < 2; e++){
    const float* pl = bflow + ((size_t)(bio * 2 + e)) * 16384;
    float v00 = pl[y0o + x0c], v01 = pl[y0o + x1c];
    float v10 = pl[y1o + x0c], v11 = pl[y1o + x1c];
    float r0 = v00 + fx * (v01 - v00);
    float r1 = v10 + fx * (v11 - v10);
    fv[e] = (r0 + fy * (r1 - r0)) * 2.f;
  }
  *(u32*)(pxb + C_CH) = pack2(fv[0], fv[1]);

  // zero tail: chunk3 ch19..31 (bytes 38..63)
  *(u16*)(pxb + 3 * C_CH + 38) = 0;
  #pragma unroll
  for (int k2 = 0; k2 < 6; k2++) *(u32*)(pxb + 3 * C_CH + 40 + 4 * k2) = 0;
}

// ---------------- MFMA correlation: D[m][n] = sum_c ref[c][w0+m] * nb[c][ih][w0+n-4] ----------
// Per wave: 16 px, all 9 dy x 9 dx. Epilogue: predicated 2B stores into chunk-major inpT.
__global__ __launch_bounds__(256) void k_corr_mfma(const u16* __restrict__ xrefT0,
    const u16* __restrict__ xnbT0, char* __restrict__ ws){
  const int tid = threadIdx.x;
  const int wv = tid >> 6, l = tid & 63;
  const int bx = blockIdx.x;
  const int bio = blockIdx.y;
  const u16* xrefT = xrefT0 + (size_t)bio * SE_XREF;
  const u16* xnbT  = xnbT0  + (size_t)bio * SE_XNB;
  const int r = bx & 255, sub = bx >> 8;
  const int h = (r & 7) * 32 + (r >> 3);     // XCD swizzle: nbT row reuse stays on-XCD
  const int w0 = (sub * 4 + wv) * 16;
  const int m16 = l & 15, g = l >> 4;

  uint4 ua = *(const uint4*)(xrefT + ((size_t)h * 256 + w0 + m16) * 32 + g * 8);
  bf16x8 av = __builtin_bit_cast(bf16x8, ua);

  size_t bOff = ((size_t)h * 272 + w0 + m16) * 32 + g * 8;
  char* ob = ws + OFF_INPT + (size_t)bio * S_INPT
             + ((size_t)(h + 1) * 258 + (w0 + 1) + g * 4) * 64;
  const f32x4 z = {0.f, 0.f, 0.f, 0.f};
  #pragma unroll
  for (int dy = 0; dy < 9; dy++){
    uint4 ub0 = *(const uint4*)(xnbT + bOff);
    uint4 ub1 = *(const uint4*)(xnbT + bOff + 512);
    bOff += 8704;                            // next padded row (272*32)
    f32x4 d0 = __builtin_amdgcn_mfma_f32_16x16x32_bf16(av, __builtin_bit_cast(bf16x8, ub0), z, 0, 0, 0);
    f32x4 d1 = __builtin_amdgcn_mfma_f32_16x16x32_bf16(av, __builtin_bit_cast(bf16x8, ub1), z, 0, 0, 0);
    #pragma unroll
    for (int j = 0; j < 4; j++){
      int dxa = m16 - g * 4 - j;             // frag0: dx = n - m
      int dxb = dxa + 16;                    // frag1: dx = n + 16 - m
      bool va = (unsigned)dxa <= 8u;
      bool vb = (unsigned)dxb <= 8u;
      if (va | vb){
        float val = va ? d0[j] : d1[j];
        int dx = va ? dxa : dxb;
        float f = lrelu(val * 0.03125f);
        int c = 34 + dy * 9 + dx;            // chunk-major channel
        *(u16*)(ob + j * 64 + (size_t)(c >> 5) * C_CH + (c & 31) * 2) = f2bf(f);
      }
    }
  }
}

// ---------------- conv0: 128->32, LDS-staged input (s-chunked), weights from global(L2) ------
// R17: block = 4 out rows x 64 px (LDS 25.3 KB -> 4+ blocks/CU resident, 16 waves/CU).
// Per s-chunk: stage [6 rows][66 px][32ch]; each input byte read once per block. grid (256, 4).
__global__ __launch_bounds__(256) void k_conv0(const u16* __restrict__ inT0, const u16* __restrict__ wt,
    const float* __restrict__ bias, u16* __restrict__ outA0){
  __shared__ __align__(16) u16 inL[12672];       // [6][66][32]
  const int tid = threadIdx.x;
  const int bx = blockIdx.x;
  const int bio = blockIdx.y;
  const u16* inT = inT0 + (size_t)bio * SE_INPT;
  u16* outA = outA0 + (size_t)bio * SE_H;
  const int rq = (bx & 7) * 8 + ((bx >> 3) & 7); // row-quad 0..63, XCD-banded
  const int ph = bx >> 6;                        // px quarter 0..3
  const int row0 = rq * 4, p0 = ph * 64;
  const int wv = tid >> 6, ln = tid & 63, l15 = ln & 15, l4 = ln >> 4;
  f32x4 acc[4][2] = {};

  for (int s = 0; s < 4; s++){
    // stage input chunk s: halo rows row0..row0+5, halo px p0..p0+65 (each byte once)
    for (int i = tid; i < 1584; i += 256){
      int rr = i / 264, q = i - rr * 264;
      int pxi = q >> 2, cq = q & 3;
      const u16* src = inT + ((size_t)s * 66564 + (size_t)(row0 + rr) * 258 + (p0 + pxi)) * 32 + cq * 8;
      ((uint4*)inL)[(rr * 66 + pxi) * 4 + cq] = *(const uint4*)src;
    }
    __syncthreads();
    #pragma unroll
    for (int ky = 0; ky < 3; ky++){
      #pragma unroll
      for (int kx = 0; kx < 3; kx++){
        const int tap = ky * 3 + kx;
        bf16x8 bv[2];
        #pragma unroll
        for (int j = 0; j < 2; j++){
          uint4 u = *(const uint4*)(wt + (size_t)(j * 16 + l15) * 1160 + tap * 128 + s * 32 + l4 * 8);
          bv[j] = __builtin_bit_cast(bf16x8, u);
        }
        #pragma unroll
        for (int t = 0; t < 4; t++){
          uint4 uai = *(const uint4*)&inL[((wv + ky) * 66 + t * 16 + l15 + kx) * 32 + l4 * 8];
          bf16x8 av = __builtin_bit_cast(bf16x8, uai);
          #pragma unroll
          for (int j = 0; j < 2; j++)
            acc[t][j] = __builtin_amdgcn_mfma_f32_16x16x32_bf16(av, bv[j], acc[t][j], 0, 0, 0);
        }
      }
    }
    __syncthreads();
  }
  // epilogue: wave wv owns out row row0+wv; bias + lrelu -> hT halo layout
  const int row = row0 + wv;
  #pragma unroll
  for (int t = 0; t < 4; t++){
    const int pxb = p0 + t * 16 + l4 * 4;
    #pragma unroll
    for (int j = 0; j < 2; j++){
      const int co = j * 16 + l15;
      const float bs = bias[co];
      #pragma unroll
      for (int r = 0; r < 4; r++){
        const int px = pxb + r;
        float v = lrelu(acc[t][j][r] + bs);
        outA[(size_t)((row + 1) * HP + px + 1) * 32 + co] = f2bf(v);
      }
    }
  }
}

// ---------------- 32-cin convs (conv1/conv2/convf), LDS-staged input, global weights ---------
// R17: block = 4 out rows x 64 px, LDS 25.3 KB, grid (256, 4).
// MODE 0: bias+lrelu -> halo outH (t1). MODE 1: +resid, lrelu -> halo outH (fea) AND fp32 out feats.
// MODE 2: flows (co 0,1) + sigmoid mask (co 2) -> fp32 out.
template<int NT, int MODE>
__global__ __launch_bounds__(256) void k_conv32(const u16* __restrict__ inT0, const u16* __restrict__ wt,
    const float* __restrict__ bias, u16* __restrict__ outH0, float* __restrict__ outF,
    const u16* __restrict__ resid0){
  __shared__ __align__(16) u16 inL[12672];       // [6][66][32]
  const int tid = threadIdx.x;
  const int bx = blockIdx.x;
  const int bio = blockIdx.y;
  const u16* inT = inT0 + (size_t)bio * SE_H;
  const int rq = (bx & 7) * 8 + ((bx >> 3) & 7);
  const int ph = bx >> 6;
  const int row0 = rq * 4, p0 = ph * 64;
  const int wv = tid >> 6, ln = tid & 63, l15 = ln & 15, l4 = ln >> 4;

  for (int i = tid; i < 1584; i += 256){
    int rr = i / 264, q = i - rr * 264;
    int pxi = q >> 2, cq = q & 3;
    const u16* src = inT + ((size_t)(row0 + rr) * 258 + (p0 + pxi)) * 32 + cq * 8;
    ((uint4*)inL)[(rr * 66 + pxi) * 4 + cq] = *(const uint4*)src;
  }
  __syncthreads();

  f32x4 acc[4][NT] = {};
  #pragma unroll
  for (int ky = 0; ky < 3; ky++){
    #pragma unroll
    for (int kx = 0; kx < 3; kx++){
      const int tap = ky * 3 + kx;
      bf16x8 bv[NT];
      #pragma unroll
      for (int j = 0; j < NT; j++){
        uint4 u = *(const uint4*)(wt + (size_t)(j * 16 + l15) * 296 + tap * 32 + l4 * 8);
        bv[j] = __builtin_bit_cast(bf16x8, u);
      }
      #pragma unroll
      for (int t = 0; t < 4; t++){
        uint4 uai = *(const uint4*)&inL[((wv + ky) * 66 + t * 16 + l15 + kx) * 32 + l4 * 8];
        bf16x8 av = __builtin_bit_cast(bf16x8, uai);
        #pragma unroll
        for (int j = 0; j < NT; j++)
          acc[t][j] = __builtin_amdgcn_mfma_f32_16x16x32_bf16(av, bv[j], acc[t][j], 0, 0, 0);
      }
    }
  }
  const int row = row0 + wv;
  #pragma unroll
  for (int t = 0; t < 4; t++){
    const int pxb = p0 + t * 16 + l4 * 4;
    #pragma unroll
    for (int j = 0; j < NT; j++){
      const int co = j * 16 + l15;
      float bs;
      if constexpr (MODE == 2) bs = (co < 3) ? bias[co] : 0.f;
      else bs = bias[co];
      #pragma unroll
      for (int r = 0; r < 4; r++){
        const int px = pxb + r;
        float v = acc[t][j][r] + bs;
        if constexpr (MODE == 0){
          v = lrelu(v);
          outH0[(size_t)bio * SE_H + (size_t)((row + 1) * HP + px + 1) * 32 + co] = f2bf(v);
        } else if constexpr (MODE == 1){
          float hres = bf2f(resid0[(size_t)bio * SE_H + (size_t)((row + 1) * HP + px + 1) * 32 + co]);
          v = lrelu(v + hres);
          outH0[(size_t)bio * SE_H + (size_t)((row + 1) * HP + px + 1) * 32 + co] = f2bf(v); // feaT
          outF[786432 + ((size_t)(bio * 32 + co)) * 65536 + (size_t)row * 256 + px] = v;     // feats
        } else {
          if (co < 2)
            outF[((size_t)(bio * 2 + co)) * 65536 + (size_t)row * 256 + px] = v;             // flows
          else if (co == 2){
            float s = 1.f / (1.f + __expf(-v));
            outF[524288 + (size_t)bio * 65536 + (size_t)row * 256 + px] = s;                 // mask
          }
        }
      }
    }
  }
}

extern "C" void kernel_launch(void* const* d_in, const int* in_sizes, int n_in,
                              void* d_out, int out_size, void* d_ws, size_t ws_size,
                              hipStream_t stream){
  float* out = (float*)d_out;

  // ---- runtime interface verification (kept from R6; encodes any mismatch into out[0]) ----
  static const int exp_sizes[12] = {8388608, 8388608, 131072, 2097152,
                                    33120, 32, 9216, 32, 9216, 32, 864, 3};
  float sent = 0.f;
  if (n_in != 12) sent = 1.0e6f;
  else if (out_size != 9175040) sent = 2.0e6f;
  else {
    for (int i = 0; i < 12; i++)
      if (in_sizes[i] != exp_sizes[i]){ sent = 3.0e6f * (1.0f + 0.01f * i); break; }
    if (sent == 0.f && ws_size < WS_NEED)
      sent = 16.0f * (float)(ws_size >> 20);
  }
  if (sent != 0.f){
    hipLaunchKernelGGL(k_sent, dim3(1), dim3(64), 0, stream, out, sent);
    return;
  }

  const float* xref  = (const float*)d_in[0];
  const float* xnb   = (const float*)d_in[1];
  const float* bflow = (const float*)d_in[2];
  const float* bfeat = (const float*)d_in[3];
  const float* w0 = (const float*)d_in[4];
  const float* b0 = (const float*)d_in[5];
  const float* w1 = (const float*)d_in[6];
  const float* b1 = (const float*)d_in[7];
  const float* w2 = (const float*)d_in[8];
  const float* b2 = (const float*)d_in[9];
  const float* wf = (const float*)d_in[10];
  const float* bf = (const float*)d_in[11];
  char* ws = (char*)d_ws;
  u16* wse   = (u16*)d_ws;
  u16* inpT  = (u16*)(ws + OFF_INPT);
  u16* hT    = (u16*)(ws + OFF_HT);
  u16* t1T   = (u16*)(ws + OFF_T1);
  u16* feaT  = (u16*)(ws + OFF_FEA);
  u16* xrefT = (u16*)(ws + OFF_XREFT);
  u16* xnbT  = (u16*)(ws + OFF_XNBT);

  hipLaunchKernelGGL(k_halo, dim3(261, 4), dim3(256), 0, stream, ws);
  hipLaunchKernelGGL(k_wprep, dim3(64), dim3(256), 0, stream, w0, w1, w2, wf, wse);
  hipLaunchKernelGGL(k_xpose, dim3(8584, 4), dim3(64), 0, stream, xref, xnb, xrefT, xnbT);
  hipLaunchKernelGGL(k_up, dim3(256, 4), dim3(256), 0, stream, bflow, bfeat, ws);
  hipLaunchKernelGGL(k_corr_mfma, dim3(1024, 4), dim3(256), 0, stream, xrefT, xnbT, ws);
  hipLaunchKernelGGL(k_conv0, dim3(256, 4), dim3(256), 0, stream, inpT, wse + E_WT0, b0, hT);
  hipLaunchKernelGGL((k_conv32<2, 0>), dim3(256, 4), dim3(256), 0, stream,
                     hT, wse + E_WT1, b1, t1T, (float*)nullptr, (const u16*)nullptr);
  hipLaunchKernelGGL((k_conv32<2, 1>), dim3(256, 4), dim3(256), 0, stream,
                     t1T, wse + E_WT2, b2, feaT, out, hT);
  hipLaunchKernelGGL((k_conv32<1, 2>), dim3(256, 4), dim3(256), 0, stream,
                     feaT, wse + E_WTF, bf, (u16*)nullptr, out, (const u16*)nullptr);
}